// Round 4
// baseline (2305.042 us; speedup 1.0000x reference)
//
#include <hip/hip_runtime.h>
#include <math.h>

#define B_ 32
#define T_ 128
#define D_ 512
#define U_ 512
#define G_ 2048   // 4U
#define NGRP 8    // batch groups
#define GB 4      // batches per group
#define WPG 32    // workgroups per group
#define NT 512    // threads per WG
#define GK 512    // K dim of precompute GEMMs
#define SLOTSTRIDE 16  // slot padding: 64B apart. word0=sc0 epoch,
                       // word4=agent mirror epoch, word8=phase0 XCD publish

__device__ __forceinline__ unsigned short f2bf(float v) {
  unsigned u = __float_as_uint(v);
  return (unsigned short)((u + 0x7FFFu + ((u >> 16) & 1u)) >> 16);
}
__device__ __forceinline__ float bf2f(unsigned short u) {
  return __uint_as_float(((unsigned)u) << 16);
}

// Device-coherence-point store (baseline path).
__device__ __forceinline__ void dev_store(float* p, float v) {
  __hip_atomic_store(p, v, __ATOMIC_RELAXED, __HIP_MEMORY_SCOPE_AGENT);
}

// Data publish: fast = sc0 (lands in the XCD's L2; same-XCD readers are
// coherent through that L2). slow = baseline agent-scope store.
__device__ __forceinline__ void pub_f32(bool fast, float* p, float v) {
  if (fast)
    asm volatile("global_store_dword %0, %1, off sc0" ::"v"(p), "v"(v)
                 : "memory");
  else
    dev_store(p, v);
}
__device__ __forceinline__ void store4_coh(bool fast, float* p, float4 v) {
  pub_f32(fast, p + 0, v.x);
  pub_f32(fast, p + 1, v.y);
  pub_f32(fast, p + 2, v.z);
  pub_f32(fast, p + 3, v.w);
}

// Fast slot poll iteration: L1 invalidate first, so the sc0 load always sees
// the XCD L2's authoritative copy (stale-L1 spin -- R1's hang mode -- is
// structurally impossible). buffer_inv only touches the issuing CU's vector
// L1 (read-only/clean lines), never loses data.
__device__ __forceinline__ unsigned ld_slot_sc0_inv(const unsigned* p) {
  unsigned r;
  asm volatile(
      "buffer_inv sc0\n\t"
      "global_load_dword %0, %1, off sc0\n\t"
      "s_waitcnt vmcnt(0)"
      : "=&v"(r)
      : "v"(p)
      : "memory");
  return r;
}

// Per-CU vector L1 invalidate before fast-mode data gathers.
__device__ __forceinline__ void inv_l1(bool fast) {
  if (fast) asm volatile("buffer_inv sc0" ::: "memory");
}

// 32 contiguous floats as 8 pipelined dwordx4 loads + ONE waitcnt.
__device__ __forceinline__ void gather32(bool fast, const float* p, float4& a0,
                                         float4& a1, float4& a2, float4& a3,
                                         float4& a4, float4& a5, float4& a6,
                                         float4& a7) {
  if (fast) {
    asm volatile(
        "global_load_dwordx4 %0, %8, off sc0\n\t"
        "global_load_dwordx4 %1, %8, off offset:16 sc0\n\t"
        "global_load_dwordx4 %2, %8, off offset:32 sc0\n\t"
        "global_load_dwordx4 %3, %8, off offset:48 sc0\n\t"
        "global_load_dwordx4 %4, %8, off offset:64 sc0\n\t"
        "global_load_dwordx4 %5, %8, off offset:80 sc0\n\t"
        "global_load_dwordx4 %6, %8, off offset:96 sc0\n\t"
        "global_load_dwordx4 %7, %8, off offset:112 sc0\n\t"
        "s_waitcnt vmcnt(0)"
        : "=&v"(a0), "=&v"(a1), "=&v"(a2), "=&v"(a3), "=&v"(a4), "=&v"(a5),
          "=&v"(a6), "=&v"(a7)
        : "v"(p)
        : "memory");
  } else {
    asm volatile(
        "global_load_dwordx4 %0, %8, off sc0 sc1\n\t"
        "global_load_dwordx4 %1, %8, off offset:16 sc0 sc1\n\t"
        "global_load_dwordx4 %2, %8, off offset:32 sc0 sc1\n\t"
        "global_load_dwordx4 %3, %8, off offset:48 sc0 sc1\n\t"
        "global_load_dwordx4 %4, %8, off offset:64 sc0 sc1\n\t"
        "global_load_dwordx4 %5, %8, off offset:80 sc0 sc1\n\t"
        "global_load_dwordx4 %6, %8, off offset:96 sc0 sc1\n\t"
        "global_load_dwordx4 %7, %8, off offset:112 sc0 sc1\n\t"
        "s_waitcnt vmcnt(0)"
        : "=&v"(a0), "=&v"(a1), "=&v"(a2), "=&v"(a3), "=&v"(a4), "=&v"(a5),
          "=&v"(a6), "=&v"(a7)
        : "v"(p)
        : "memory");
  }
}

__device__ __forceinline__ float4 load4_coh(bool fast, const float* p) {
  float4 r;
  if (fast)
    asm volatile(
        "global_load_dwordx4 %0, %1, off sc0\n\t"
        "s_waitcnt vmcnt(0)"
        : "=&v"(r)
        : "v"(p)
        : "memory");
  else
    asm volatile(
        "global_load_dwordx4 %0, %1, off sc0 sc1\n\t"
        "s_waitcnt vmcnt(0)"
        : "=&v"(r)
        : "v"(p)
        : "memory");
  return r;
}

// ---------------------------------------------------------------------------
// Precompute GEMM: C[M,N] = A[M,512] @ W[512,N] + bias  (bias may be null)
// MODE 1: bf16 row-major; MODE 2: fp32 (B,U,T)-transposed
// ---------------------------------------------------------------------------
template <int MODE>
__global__ __launch_bounds__(256) void gemm_bias_t(const float* __restrict__ A,
                                                   const float* __restrict__ W,
                                                   const float* __restrict__ bias,
                                                   void* __restrict__ Cout, int N) {
  __shared__ float As[16][68];
  __shared__ float Ws[16][64];
  const int tid = threadIdx.x;
  const int rowbase = blockIdx.y * 64;
  const int colbase = blockIdx.x * 64;
  const int ty = tid >> 4, tx = tid & 15;
  const int ar = tid >> 2, ak = (tid & 3) << 2;
  const int wk = tid >> 4, wc = (tid & 15) << 2;
  float acc[4][4] = {{0.f, 0.f, 0.f, 0.f}};
  for (int k0 = 0; k0 < GK; k0 += 16) {
    float4 av = *(const float4*)(A + (size_t)(rowbase + ar) * GK + k0 + ak);
    float4 wv = *(const float4*)(W + (size_t)(k0 + wk) * N + colbase + wc);
    __syncthreads();
    As[ak + 0][ar] = av.x;
    As[ak + 1][ar] = av.y;
    As[ak + 2][ar] = av.z;
    As[ak + 3][ar] = av.w;
    *(float4*)(&Ws[wk][wc]) = wv;
    __syncthreads();
#pragma unroll
    for (int kk = 0; kk < 16; ++kk) {
      float4 a = *(const float4*)(&As[kk][ty << 2]);
      float4 wv2 = *(const float4*)(&Ws[kk][tx << 2]);
      float a4[4] = {a.x, a.y, a.z, a.w};
      float w4[4] = {wv2.x, wv2.y, wv2.z, wv2.w};
#pragma unroll
      for (int i = 0; i < 4; ++i)
#pragma unroll
        for (int jj = 0; jj < 4; ++jj) acc[i][jj] += a4[i] * w4[jj];
    }
  }
  float4 bv = bias ? *(const float4*)(bias + colbase + (tx << 2))
                   : make_float4(0.f, 0.f, 0.f, 0.f);
#pragma unroll
  for (int i = 0; i < 4; ++i) {
    const int row = rowbase + (ty << 2) + i;
    float o[4] = {acc[i][0] + bv.x, acc[i][1] + bv.y, acc[i][2] + bv.z,
                  acc[i][3] + bv.w};
    if (MODE == 1) {
      ushort4 ob;
      ob.x = f2bf(o[0]); ob.y = f2bf(o[1]); ob.z = f2bf(o[2]); ob.w = f2bf(o[3]);
      *(ushort4*)((unsigned short*)Cout + (size_t)row * N + colbase + (tx << 2)) = ob;
    } else {
      const int b = row >> 7, tt = row & 127;
#pragma unroll
      for (int jj = 0; jj < 4; ++jj) {
        int u = colbase + (tx << 2) + jj;
        ((float*)Cout)[((size_t)b * U_ + u) * T_ + tt] = o[jj];
      }
    }
  }
}

__device__ __forceinline__ float tanh_fast(float x) {
  return 1.f - 2.f / (__expf(2.f * x) + 1.f);
}

// Split-phase RMW-free barrier. Arrive: explicit vmcnt(0) (inline-asm data
// stores are invisible to the compiler's barrier lowering) + syncthreads +
// own padded slot store. Fast mode: sc0 slot store (XCD-L2-local, ~200-400cy
// visibility) PLUS an agent-scope mirror at word 4 (deadlock safety net).
// Wait: parallel 32-slot poll. Fast mode polls word 0 with buffer_inv+sc0
// (L2-authoritative every iteration); after 4096 tries sticky-escape to
// agent polls of the mirror -> correct under any coherence interpretation.
// Independent work goes between arrive and wait.
__device__ __forceinline__ void grp_arrive(bool fast, unsigned* slots, int w,
                                           unsigned epoch) {
  asm volatile("s_waitcnt vmcnt(0)" ::: "memory");
  __syncthreads();
  if (threadIdx.x == 0) {
    if (fast) {
      asm volatile("global_store_dword %0, %1, off sc0" ::"v"(
                       &slots[w * SLOTSTRIDE]),
                   "v"(epoch)
                   : "memory");
      __hip_atomic_store(&slots[w * SLOTSTRIDE + 4], epoch, __ATOMIC_RELAXED,
                         __HIP_MEMORY_SCOPE_AGENT);
    } else {
      __hip_atomic_store(&slots[w * SLOTSTRIDE], epoch, __ATOMIC_RELAXED,
                         __HIP_MEMORY_SCOPE_AGENT);
    }
  }
}
__device__ __forceinline__ void grp_wait(bool fast, const unsigned* slots,
                                         unsigned epoch, int* esc_flag) {
  if (threadIdx.x < 64) {
    bool esc = !fast || (*esc_flag != 0);
    int tries = 0;
    bool done = false;
    const unsigned* pf = &slots[threadIdx.x * SLOTSTRIDE];
    const unsigned* pe = &slots[threadIdx.x * SLOTSTRIDE + (fast ? 4 : 0)];
    do {
      unsigned v;
      if (threadIdx.x < WPG) {
        v = esc ? __hip_atomic_load(pe, __ATOMIC_RELAXED,
                                    __HIP_MEMORY_SCOPE_AGENT)
                : ld_slot_sc0_inv(pf);
      } else {
        v = epoch;
      }
      done = __all(v >= epoch);
      if (!done && !esc && ++tries > 4096) {
        esc = true;
        if (threadIdx.x == 0) *esc_flag = 1;
      }
    } while (!done);
  }
  __syncthreads();
}

// ---------------------------------------------------------------------------
// Weight-stationary recurrence, split-phase barriers. 8 groups x 32 WGs x
// 512 threads. B1 wait hidden under the h@Rk matvec; B2 wait hides the xk
// prefetch. sp layout (b,t,w): reader's 32 partials = one 128B block.
// Phase 0: each WG publishes HW_REG_XCC_ID into word 8 of its own barrier
// slot (zeroed by the existing memset). If every XCD holds exactly 32 WGs,
// groups remap to bg=xcd / w=rank-in-xcd so ALL group-internal traffic
// (sp, h, barrier epochs) stays in that XCD's shared L2 (sc0, ~200-400cy)
// instead of the device coherence point (~900cy). Any other placement ->
// baseline agent-scope path. Correctness never depends on dispatch mapping
// (G16); only speed does. R3 verified: fast path engages (WRITE_SIZE
// 567->86 MB) and sc0+inv data gathers are correct (absmax == baseline).
// ---------------------------------------------------------------------------
__global__ __launch_bounds__(NT) void attlstm_rec(
    const unsigned short* __restrict__ xk,  // (B,T,4U) bf16
    const unsigned short* __restrict__ xA,  // (B,T,4U) bf16
    const float* __restrict__ attxT,        // (B,U,T) fp32
    const float* __restrict__ Rk,           // (U,4U)
    const float* __restrict__ Um,           // (U,U)
    const float* __restrict__ V,            // (U)
    float* __restrict__ h_pub,              // (NGRP,GB,U)
    float* __restrict__ sp_g,               // (NGRP,GB,T,WPG)
    unsigned* __restrict__ bars,            // (NGRP,WPG*SLOTSTRIDE)
    float* __restrict__ out) {              // (B,T,U)
  const int tid = threadIdx.x;

  // ===== Phase 0 (one-time): XCD placement discovery & group remap =====
  __shared__ unsigned char xcd_l[256];
  __shared__ int map_s[3];
  __shared__ int esc_s;
  unsigned myxcd;
  asm volatile("s_getreg_b32 %0, hwreg(HW_REG_XCC_ID)" : "=s"(myxcd));
  if (tid == 0)
    __hip_atomic_store(&bars[(unsigned)blockIdx.x * SLOTSTRIDE + 8],
                       (myxcd & 0xffu) + 1u, __ATOMIC_RELAXED,
                       __HIP_MEMORY_SCOPE_AGENT);
  if (tid < 256) {
    unsigned v;
    do {  // same co-residency requirement as the baseline's own barriers
      v = __hip_atomic_load(&bars[(unsigned)tid * SLOTSTRIDE + 8],
                            __ATOMIC_RELAXED, __HIP_MEMORY_SCOPE_AGENT);
    } while (v == 0u);
    xcd_l[tid] = (unsigned char)(v - 1u);
  }
  if (tid == 0) esc_s = 0;
  __syncthreads();
  if (tid == 0) {
    int cnt[8] = {0, 0, 0, 0, 0, 0, 0, 0};
    int rank = 0;
    bool ok = true;
    const int myb = (int)blockIdx.x;
    const int myx = (int)(unsigned)xcd_l[myb];
    for (int i = 0; i < 256; ++i) {
      int xc = (int)(unsigned)xcd_l[i];
      if (xc > 7) { ok = false; break; }
      cnt[xc]++;
      if (i < myb && xc == myx) rank++;
    }
    if (ok)
      for (int i = 0; i < 8; ++i) ok &= (cnt[i] == 32);
    map_s[0] = ok ? myx : (myb & 7);
    map_s[1] = ok ? rank : (myb >> 3);
    map_s[2] = ok ? 1 : 0;
  }
  __syncthreads();
  const int bg = map_s[0];
  const int w = map_s[1];
  const bool fast = (map_s[2] != 0);

  const int u0 = w * 16;
  const int tk = tid >> 4;  // 0..31 (K-chunk of 16)
  const int tc = tid & 15;  // col-quad id
  const int gcol = (tc >> 2) * U_ + u0 + (tc & 3) * 4;
  const int wv = tid >> 6;
  const int lane = tid & 63;
  const int bS = tid >> 7;
  const int tS = tid & 127;
  const int rb = tid >> 6;  // reducer role (tid<256)
  const int rc = tid & 63;
  const int rtc = rc >> 2, rcomp = rc & 3;
  const int rg = rtc >> 2;
  const int rui = ((rtc & 3) << 2) | rcomp;
  const int rcol = rg * U_ + u0 + rui;

  __shared__ float attx_l[16 * GB * T_];  // 32 KB
  __shared__ float h_s[GB][U_];           // 8 KB
  __shared__ float4 red2[8][GB][17];
  __shared__ float hUred[8][GB][17];
  __shared__ float sc_s[GB][T_];
  __shared__ float hU_s[GB][16];
  __shared__ float act_s[GB][64];
  __shared__ float c_s[GB][16];
  __shared__ float lsum_s[8];
  __shared__ float Vs_l[16];

  float4 Rw[16];
  float Uw[16];
#pragma unroll
  for (int i = 0; i < 16; ++i)
    Rw[i] = *(const float4*)(Rk + (size_t)(tk * 16 + i) * G_ + gcol);
#pragma unroll
  for (int i = 0; i < 16; ++i)
    Uw[i] = Um[(size_t)(tk * 16 + i) * U_ + u0 + tc];

  for (int idx = tid; idx < 16 * GB * T_; idx += NT) {
    int uc = idx >> 9;
    int b = (idx >> 7) & 3;
    int tt = idx & 127;
    attx_l[idx] = attxT[((size_t)(bg * GB + b) * U_ + u0 + uc) * T_ + tt];
  }
  for (int i = tid; i < GB * U_; i += NT) ((float*)h_s)[i] = 0.f;
  if (tid < GB * 16) ((float*)c_s)[tid] = 0.f;
  if (tid < 16) Vs_l[tid] = V[u0 + tid];
  unsigned* slots = bars + bg * (WPG * SLOTSTRIDE);
  unsigned epoch = 0;
  float* hpg = h_pub + (size_t)bg * GB * U_;
  float* spg = sp_g + (size_t)bg * GB * T_ * WPG;
  float xkv = 0.f;
  if (tid < 256) xkv = bf2f(xk[((size_t)(bg * GB + rb) * T_ + 0) * G_ + rcol]);
  __syncthreads();

  for (int t = 0; t < T_; ++t) {
    // ===== P1a: hU partial (h@Um own u-slice) -> scores -> sp publish
    float hUa[GB];
#pragma unroll
    for (int b = 0; b < GB; ++b) {
      float hu = 0.f;
      const float* hp = &h_s[b][tk * 16];
#pragma unroll
      for (int i = 0; i < 16; ++i) hu += hp[i] * Uw[i];
      hUa[b] = hu;
    }
#pragma unroll
    for (int b = 0; b < GB; ++b) {
      float hu = hUa[b];
      hu += __shfl_down(hu, 32);
      hu += __shfl_down(hu, 16);
      if (lane < 16) hUred[wv][b][lane] = hu;
    }
    __syncthreads();
    if (tid < 64) {
      int b = tid >> 4, u = tid & 15;
      float s = 0.f;
#pragma unroll
      for (int k = 0; k < 8; ++k) s += hUred[k][b][u];
      hU_s[b][u] = s;
    }
    __syncthreads();
    {  // score partials over own 16-u slice, all (b,t'); layout (b,t',w)
      float s = 0.f;
      const float* ax = &attx_l[bS * T_ + tS];
#pragma unroll
      for (int uc = 0; uc < 16; ++uc) {
        float e = tanh_fast(ax[uc * (GB * T_)] + hU_s[bS][uc]);
        s += e * Vs_l[uc];
      }
      pub_f32(fast, &spg[((size_t)bS * T_ + tS) * WPG + w], s);
    }
    grp_arrive(fast, slots, w, ++epoch);  // B1 arrive

    // ===== B1 shadow: the big h@Rk matvec (independent of sp)
    float4 accR[GB];
#pragma unroll
    for (int b = 0; b < GB; ++b) {
      float4 a = make_float4(0.f, 0.f, 0.f, 0.f);
      const float* hp = &h_s[b][tk * 16];
#pragma unroll
      for (int i = 0; i < 16; ++i) {
        float hv = hp[i];
        a.x += hv * Rw[i].x;
        a.y += hv * Rw[i].y;
        a.z += hv * Rw[i].z;
        a.w += hv * Rw[i].w;
      }
      accR[b] = a;
    }
    grp_wait(fast, slots, epoch, &esc_s);  // B1 wait
    inv_l1(fast);                          // L1 clean before fast gathers

    // ===== P2: wide gather -> softmax (no max pass) -> fold -> LSTM
    {
      const float* spp = spg + ((size_t)bS * T_ + tS) * WPG;
      float4 a0, a1, a2, a3, a4, a5, a6, a7;
      gather32(fast, spp, a0, a1, a2, a3, a4, a5, a6, a7);
      float s = (((a0.x + a0.y) + (a0.z + a0.w)) + ((a1.x + a1.y) + (a1.z + a1.w))) +
                (((a2.x + a2.y) + (a2.z + a2.w)) + ((a3.x + a3.y) + (a3.z + a3.w))) +
                (((a4.x + a4.y) + (a4.z + a4.w)) + ((a5.x + a5.y) + (a5.z + a5.w))) +
                (((a6.x + a6.y) + (a6.z + a6.w)) + ((a7.x + a7.y) + (a7.z + a7.w)));
      float e = __expf(s);  // |s| <= ||V||_1 ~ 20: fp32-safe without shift
      sc_s[bS][tS] = e;
      float ls = e;  // lanes of this wave share bS
      for (int o = 32; o > 0; o >>= 1) ls += __shfl_down(ls, o);
      if (lane == 0) lsum_s[wv] = ls;
    }
    __syncthreads();
#pragma unroll
    for (int b = 0; b < GB; ++b) {
      const unsigned short* xap =
          xA + ((size_t)(bg * GB + b) * T_ + tk * 4) * G_ + gcol;
      float4 az = make_float4(0.f, 0.f, 0.f, 0.f);
#pragma unroll
      for (int i = 0; i < 4; ++i) {
        ushort4 xv = *(const ushort4*)(xap + (size_t)i * G_);
        float al = sc_s[b][tk * 4 + i];
        az.x += al * bf2f(xv.x);
        az.y += al * bf2f(xv.y);
        az.z += al * bf2f(xv.z);
        az.w += al * bf2f(xv.w);
      }
      float il = 1.f / (lsum_s[2 * b] + lsum_s[2 * b + 1]);
      float4 comb;
      comb.x = accR[b].x + il * az.x;
      comb.y = accR[b].y + il * az.y;
      comb.z = accR[b].z + il * az.z;
      comb.w = accR[b].w + il * az.w;
      comb.x += __shfl_down(comb.x, 32);
      comb.y += __shfl_down(comb.y, 32);
      comb.z += __shfl_down(comb.z, 32);
      comb.w += __shfl_down(comb.w, 32);
      comb.x += __shfl_down(comb.x, 16);
      comb.y += __shfl_down(comb.y, 16);
      comb.z += __shfl_down(comb.z, 16);
      comb.w += __shfl_down(comb.w, 16);
      if (lane < 16) red2[wv][b][lane] = comb;
    }
    __syncthreads();
    if (tid < 256) {
      float gsum = xkv;
      const float* r2 = (const float*)red2;
#pragma unroll
      for (int k = 0; k < 8; ++k)
        gsum += r2[(((size_t)(k * GB + rb) * 17) + rtc) * 4 + rcomp];
      float gv = (rg == 2) ? tanh_fast(gsum)
                           : fminf(fmaxf(0.2f * gsum + 0.5f, 0.f), 1.f);
      act_s[rb][rg * 16 + rui] = gv;
    }
    __syncthreads();
    if (tid < 16) {
      int b = tid >> 2, uq = tid & 3;
      float4 hn4;
#pragma unroll
      for (int k2 = 0; k2 < 4; ++k2) {
        int ui = uq * 4 + k2;
        float i_ = act_s[b][ui];
        float f_ = act_s[b][16 + ui];
        float g_ = act_s[b][32 + ui];
        float o_ = act_s[b][48 + ui];
        float cn = f_ * c_s[b][ui] + i_ * g_;
        c_s[b][ui] = cn;
        ((float*)&hn4)[k2] = o_ * tanh_fast(cn);
      }
      int gb = bg * GB + b;
      store4_coh(fast, &hpg[(size_t)b * U_ + u0 + uq * 4], hn4);
      *(float4*)(out + ((size_t)gb * T_ + t) * U_ + u0 + uq * 4) = hn4;
    }
    grp_arrive(fast, slots, w, ++epoch);  // B2 arrive

    // ===== B2 shadow: prefetch next step's xk
    int tn = (t + 1 < T_) ? t + 1 : t;
    float xkv_n = 0.f;
    if (tid < 256)
      xkv_n = bf2f(xk[((size_t)(bg * GB + rb) * T_ + tn) * G_ + rcol]);
    grp_wait(fast, slots, epoch, &esc_s);  // B2 wait
    inv_l1(fast);                          // L1 clean before h gather

    {
      float4 hv = load4_coh(fast, hpg + tid * 4);
      *(float4*)&((float*)h_s)[tid * 4] = hv;
    }
    xkv = xkv_n;
    __syncthreads();
  }
}

// ---------------------------------------------------------------------------
extern "C" void kernel_launch(void* const* d_in, const int* in_sizes, int n_in,
                              void* d_out, int out_size, void* d_ws,
                              size_t ws_size, hipStream_t stream) {
  (void)in_sizes;
  (void)n_in;
  (void)out_size;
  (void)ws_size;
  const float* x = (const float*)d_in[0];
  const float* Wk = (const float*)d_in[1];
  const float* Rk = (const float*)d_in[2];
  const float* Ak = (const float*)d_in[3];
  const float* Wa = (const float*)d_in[4];
  const float* Ua = (const float*)d_in[5];
  const float* Va = (const float*)d_in[6];
  const float* bias = (const float*)d_in[7];
  const float* ba = (const float*)d_in[8];
  float* out = (float*)d_out;

  char* ws = (char*)d_ws;
  unsigned short* xk_b = (unsigned short*)(ws);            // 16 MiB
  unsigned short* xA_b = (unsigned short*)(ws + 16777216); // 16 MiB
  float* attxT = (float*)(ws + 33554432);                  // 8 MiB
  float* h_pub = (float*)(ws + 41943040);                  // 64 KiB
  float* sp_g = (float*)(ws + 42008576);                   // 512 KiB
  unsigned* bars = (unsigned*)(ws + 42532864);             // 16 KiB

  gemm_bias_t<1><<<dim3(G_ / 64, (B_ * T_) / 64), 256, 0, stream>>>(
      x, Wk, bias, xk_b, G_);
  gemm_bias_t<1><<<dim3(G_ / 64, (B_ * T_) / 64), 256, 0, stream>>>(
      x, Ak, nullptr, xA_b, G_);
  gemm_bias_t<2><<<dim3(U_ / 64, (B_ * T_) / 64), 256, 0, stream>>>(
      x, Wa, ba, attxT, U_);
  (void)hipMemsetAsync(bars, 0, NGRP * WPG * SLOTSTRIDE * sizeof(unsigned),
                       stream);

  attlstm_rec<<<dim3(NGRP * WPG), dim3(NT), 0, stream>>>(
      xk_b, xA_b, attxT, Rk, Ua, Va, h_pub, sp_g, bars, out);
}

// Round 5
// 1771.164 us; speedup vs baseline: 1.3014x; 1.3014x over previous
//
#include <hip/hip_runtime.h>
#include <math.h>

#define B_ 32
#define T_ 128
#define D_ 512
#define U_ 512
#define G_ 2048   // 4U
#define NGRP 8    // batch groups
#define GB 4      // batches per group
#define WPG 32    // workgroups per group
#define NT 512    // threads per WG
#define GK 512    // K dim of precompute GEMMs
#define SLOTSTRIDE 16  // slot padding: 64B apart. word0=epoch, word8=XCD pub

__device__ __forceinline__ unsigned short f2bf(float v) {
  unsigned u = __float_as_uint(v);
  return (unsigned short)((u + 0x7FFFu + ((u >> 16) & 1u)) >> 16);
}
__device__ __forceinline__ float bf2f(unsigned short u) {
  return __uint_as_float(((unsigned)u) << 16);
}

// Device-coherence-point store (baseline path).
__device__ __forceinline__ void dev_store(float* p, float v) {
  __hip_atomic_store(p, v, __ATOMIC_RELAXED, __HIP_MEMORY_SCOPE_AGENT);
}

// Data publish: fast = sc0 (lands in the XCD's L2; same-XCD readers are
// coherent through that L2). slow = baseline agent-scope store.
__device__ __forceinline__ void pub_f32(bool fast, float* p, float v) {
  if (fast)
    asm volatile("global_store_dword %0, %1, off sc0" ::"v"(p), "v"(v)
                 : "memory");
  else
    dev_store(p, v);
}
__device__ __forceinline__ void store4_coh(bool fast, float* p, float4 v) {
  pub_f32(fast, p + 0, v.x);
  pub_f32(fast, p + 1, v.y);
  pub_f32(fast, p + 2, v.z);
  pub_f32(fast, p + 3, v.w);
}

// sc0 slot load for the fast poll (L2 latency). Escape path uses the
// baseline __hip_atomic_load, so a stale-L1 world cannot deadlock.
// NOTE (R4 post-mortem): NO buffer_inv inside the poll loop — per-iteration
// L1 invalidation nuked compute-phase locality and serialized the poll
// (1397 -> 2040 us). R3's structure (this one) is the verified optimum.
__device__ __forceinline__ unsigned ld_slot_sc0(const unsigned* p) {
  unsigned r;
  asm volatile(
      "global_load_dword %0, %1, off sc0\n\t"
      "s_waitcnt vmcnt(0)"
      : "=&v"(r)
      : "v"(p)
      : "memory");
  return r;
}

// Per-CU vector L1 invalidate before fast-mode data gathers (once per wait).
__device__ __forceinline__ void inv_l1(bool fast) {
  if (fast) asm volatile("buffer_inv sc0" ::: "memory");
}

// 32 contiguous floats as 8 pipelined dwordx4 loads + ONE waitcnt.
__device__ __forceinline__ void gather32(bool fast, const float* p, float4& a0,
                                         float4& a1, float4& a2, float4& a3,
                                         float4& a4, float4& a5, float4& a6,
                                         float4& a7) {
  if (fast) {
    asm volatile(
        "global_load_dwordx4 %0, %8, off sc0\n\t"
        "global_load_dwordx4 %1, %8, off offset:16 sc0\n\t"
        "global_load_dwordx4 %2, %8, off offset:32 sc0\n\t"
        "global_load_dwordx4 %3, %8, off offset:48 sc0\n\t"
        "global_load_dwordx4 %4, %8, off offset:64 sc0\n\t"
        "global_load_dwordx4 %5, %8, off offset:80 sc0\n\t"
        "global_load_dwordx4 %6, %8, off offset:96 sc0\n\t"
        "global_load_dwordx4 %7, %8, off offset:112 sc0\n\t"
        "s_waitcnt vmcnt(0)"
        : "=&v"(a0), "=&v"(a1), "=&v"(a2), "=&v"(a3), "=&v"(a4), "=&v"(a5),
          "=&v"(a6), "=&v"(a7)
        : "v"(p)
        : "memory");
  } else {
    asm volatile(
        "global_load_dwordx4 %0, %8, off sc0 sc1\n\t"
        "global_load_dwordx4 %1, %8, off offset:16 sc0 sc1\n\t"
        "global_load_dwordx4 %2, %8, off offset:32 sc0 sc1\n\t"
        "global_load_dwordx4 %3, %8, off offset:48 sc0 sc1\n\t"
        "global_load_dwordx4 %4, %8, off offset:64 sc0 sc1\n\t"
        "global_load_dwordx4 %5, %8, off offset:80 sc0 sc1\n\t"
        "global_load_dwordx4 %6, %8, off offset:96 sc0 sc1\n\t"
        "global_load_dwordx4 %7, %8, off offset:112 sc0 sc1\n\t"
        "s_waitcnt vmcnt(0)"
        : "=&v"(a0), "=&v"(a1), "=&v"(a2), "=&v"(a3), "=&v"(a4), "=&v"(a5),
          "=&v"(a6), "=&v"(a7)
        : "v"(p)
        : "memory");
  }
}

__device__ __forceinline__ float4 load4_coh(bool fast, const float* p) {
  float4 r;
  if (fast)
    asm volatile(
        "global_load_dwordx4 %0, %1, off sc0\n\t"
        "s_waitcnt vmcnt(0)"
        : "=&v"(r)
        : "v"(p)
        : "memory");
  else
    asm volatile(
        "global_load_dwordx4 %0, %1, off sc0 sc1\n\t"
        "s_waitcnt vmcnt(0)"
        : "=&v"(r)
        : "v"(p)
        : "memory");
  return r;
}

// ---------------------------------------------------------------------------
// Precompute GEMM: C[M,N] = A[M,512] @ W[512,N] + bias  (bias may be null)
// MODE 1: bf16 row-major; MODE 2: fp32 (B,U,T)-transposed
// ---------------------------------------------------------------------------
template <int MODE>
__global__ __launch_bounds__(256) void gemm_bias_t(const float* __restrict__ A,
                                                   const float* __restrict__ W,
                                                   const float* __restrict__ bias,
                                                   void* __restrict__ Cout, int N) {
  __shared__ float As[16][68];
  __shared__ float Ws[16][64];
  const int tid = threadIdx.x;
  const int rowbase = blockIdx.y * 64;
  const int colbase = blockIdx.x * 64;
  const int ty = tid >> 4, tx = tid & 15;
  const int ar = tid >> 2, ak = (tid & 3) << 2;
  const int wk = tid >> 4, wc = (tid & 15) << 2;
  float acc[4][4] = {{0.f, 0.f, 0.f, 0.f}};
  for (int k0 = 0; k0 < GK; k0 += 16) {
    float4 av = *(const float4*)(A + (size_t)(rowbase + ar) * GK + k0 + ak);
    float4 wv = *(const float4*)(W + (size_t)(k0 + wk) * N + colbase + wc);
    __syncthreads();
    As[ak + 0][ar] = av.x;
    As[ak + 1][ar] = av.y;
    As[ak + 2][ar] = av.z;
    As[ak + 3][ar] = av.w;
    *(float4*)(&Ws[wk][wc]) = wv;
    __syncthreads();
#pragma unroll
    for (int kk = 0; kk < 16; ++kk) {
      float4 a = *(const float4*)(&As[kk][ty << 2]);
      float4 wv2 = *(const float4*)(&Ws[kk][tx << 2]);
      float a4[4] = {a.x, a.y, a.z, a.w};
      float w4[4] = {wv2.x, wv2.y, wv2.z, wv2.w};
#pragma unroll
      for (int i = 0; i < 4; ++i)
#pragma unroll
        for (int jj = 0; jj < 4; ++jj) acc[i][jj] += a4[i] * w4[jj];
    }
  }
  float4 bv = bias ? *(const float4*)(bias + colbase + (tx << 2))
                   : make_float4(0.f, 0.f, 0.f, 0.f);
#pragma unroll
  for (int i = 0; i < 4; ++i) {
    const int row = rowbase + (ty << 2) + i;
    float o[4] = {acc[i][0] + bv.x, acc[i][1] + bv.y, acc[i][2] + bv.z,
                  acc[i][3] + bv.w};
    if (MODE == 1) {
      ushort4 ob;
      ob.x = f2bf(o[0]); ob.y = f2bf(o[1]); ob.z = f2bf(o[2]); ob.w = f2bf(o[3]);
      *(ushort4*)((unsigned short*)Cout + (size_t)row * N + colbase + (tx << 2)) = ob;
    } else {
      const int b = row >> 7, tt = row & 127;
#pragma unroll
      for (int jj = 0; jj < 4; ++jj) {
        int u = colbase + (tx << 2) + jj;
        ((float*)Cout)[((size_t)b * U_ + u) * T_ + tt] = o[jj];
      }
    }
  }
}

__device__ __forceinline__ float tanh_fast(float x) {
  return 1.f - 2.f / (__expf(2.f * x) + 1.f);
}

// Split-phase RMW-free barrier (R3-verified structure). Arrive: explicit
// vmcnt(0) (inline-asm data stores are invisible to the compiler's barrier
// lowering) + syncthreads + own padded slot store (agent scope). Wait:
// parallel 32-slot poll; fast mode polls with sc0 (L2) and sticky-escapes
// to the agent-scope poll after 512 tries -> deadlock-impossible in any
// coherence interpretation. Independent work goes between arrive and wait.
__device__ __forceinline__ void grp_arrive(unsigned* slots, int w,
                                           unsigned epoch) {
  asm volatile("s_waitcnt vmcnt(0)" ::: "memory");
  __syncthreads();
  if (threadIdx.x == 0)
    __hip_atomic_store(&slots[w * SLOTSTRIDE], epoch, __ATOMIC_RELAXED,
                       __HIP_MEMORY_SCOPE_AGENT);
}
__device__ __forceinline__ void grp_wait(bool fast, const unsigned* slots,
                                         unsigned epoch, int* esc_flag) {
  if (threadIdx.x < 64) {
    bool esc = !fast || (*esc_flag != 0);
    int tries = 0;
    bool done = false;
    do {
      unsigned v;
      if (threadIdx.x < WPG) {
        v = esc ? __hip_atomic_load(&slots[threadIdx.x * SLOTSTRIDE],
                                    __ATOMIC_RELAXED, __HIP_MEMORY_SCOPE_AGENT)
                : ld_slot_sc0(&slots[threadIdx.x * SLOTSTRIDE]);
      } else {
        v = epoch;
      }
      done = __all(v >= epoch);
      if (!done && !esc && ++tries > 512) {
        esc = true;
        if (threadIdx.x == 0) *esc_flag = 1;
      }
    } while (!done);
  }
  __syncthreads();
}

// ---------------------------------------------------------------------------
// Weight-stationary recurrence, split-phase barriers. 8 groups x 32 WGs x
// 512 threads. B1 wait hidden under the h@Rk matvec; B2 wait hides the xk
// prefetch. sp layout (b,t,w): reader's 32 partials = one 128B block.
// Phase 0: each WG publishes HW_REG_XCC_ID into word 8 of its own barrier
// slot; if every XCD holds exactly 32 WGs, groups remap to bg=xcd /
// w=rank-in-xcd so all group-internal bulk traffic (sp, h) stays in that
// XCD's shared L2 (sc0) instead of the device coherence point. Fallback ->
// baseline path. R3 verified: fast path engages (WRITE_SIZE 567->86 MB).
// R5 NEW: xA fold addresses are time-invariant -> hoisted into registers
// (float4 xAv[GB][4], static indexing) before the T-loop; removes 64 KB/WG
// of L2 reads + ~128 VALU bf16-cvt ops from every one of the 128 steps.
// ---------------------------------------------------------------------------
__global__ __launch_bounds__(NT) void attlstm_rec(
    const unsigned short* __restrict__ xk,  // (B,T,4U) bf16
    const unsigned short* __restrict__ xA,  // (B,T,4U) bf16
    const float* __restrict__ attxT,        // (B,U,T) fp32
    const float* __restrict__ Rk,           // (U,4U)
    const float* __restrict__ Um,           // (U,U)
    const float* __restrict__ V,            // (U)
    float* __restrict__ h_pub,              // (NGRP,GB,U)
    float* __restrict__ sp_g,               // (NGRP,GB,T,WPG)
    unsigned* __restrict__ bars,            // (NGRP,WPG*SLOTSTRIDE)
    float* __restrict__ out) {              // (B,T,U)
  const int tid = threadIdx.x;

  // ===== Phase 0 (one-time): XCD placement discovery & group remap =====
  __shared__ unsigned char xcd_l[256];
  __shared__ int map_s[3];
  __shared__ int esc_s;
  unsigned myxcd;
  asm volatile("s_getreg_b32 %0, hwreg(HW_REG_XCC_ID)" : "=s"(myxcd));
  if (tid == 0)
    __hip_atomic_store(&bars[(unsigned)blockIdx.x * SLOTSTRIDE + 8],
                       (myxcd & 0xffu) + 1u, __ATOMIC_RELAXED,
                       __HIP_MEMORY_SCOPE_AGENT);
  if (tid < 256) {
    unsigned v;
    do {  // same co-residency requirement as the baseline's own barriers
      v = __hip_atomic_load(&bars[(unsigned)tid * SLOTSTRIDE + 8],
                            __ATOMIC_RELAXED, __HIP_MEMORY_SCOPE_AGENT);
    } while (v == 0u);
    xcd_l[tid] = (unsigned char)(v - 1u);
  }
  if (tid == 0) esc_s = 0;
  __syncthreads();
  if (tid == 0) {
    int cnt[8] = {0, 0, 0, 0, 0, 0, 0, 0};
    int rank = 0;
    bool ok = true;
    const int myb = (int)blockIdx.x;
    const int myx = (int)(unsigned)xcd_l[myb];
    for (int i = 0; i < 256; ++i) {
      int xc = (int)(unsigned)xcd_l[i];
      if (xc > 7) { ok = false; break; }
      cnt[xc]++;
      if (i < myb && xc == myx) rank++;
    }
    if (ok)
      for (int i = 0; i < 8; ++i) ok &= (cnt[i] == 32);
    map_s[0] = ok ? myx : (myb & 7);
    map_s[1] = ok ? rank : (myb >> 3);
    map_s[2] = ok ? 1 : 0;
  }
  __syncthreads();
  const int bg = map_s[0];
  const int w = map_s[1];
  const bool fast = (map_s[2] != 0);

  const int u0 = w * 16;
  const int tk = tid >> 4;  // 0..31 (K-chunk of 16)
  const int tc = tid & 15;  // col-quad id
  const int gcol = (tc >> 2) * U_ + u0 + (tc & 3) * 4;
  const int wv = tid >> 6;
  const int lane = tid & 63;
  const int bS = tid >> 7;
  const int tS = tid & 127;
  const int rb = tid >> 6;  // reducer role (tid<256)
  const int rc = tid & 63;
  const int rtc = rc >> 2, rcomp = rc & 3;
  const int rg = rtc >> 2;
  const int rui = ((rtc & 3) << 2) | rcomp;
  const int rcol = rg * U_ + u0 + rui;

  __shared__ float attx_l[16 * GB * T_];  // 32 KB
  __shared__ float h_s[GB][U_];           // 8 KB
  __shared__ float4 red2[8][GB][17];
  __shared__ float hUred[8][GB][17];
  __shared__ float sc_s[GB][T_];
  __shared__ float hU_s[GB][16];
  __shared__ float act_s[GB][64];
  __shared__ float c_s[GB][16];
  __shared__ float lsum_s[8];
  __shared__ float Vs_l[16];

  float4 Rw[16];
  float Uw[16];
#pragma unroll
  for (int i = 0; i < 16; ++i)
    Rw[i] = *(const float4*)(Rk + (size_t)(tk * 16 + i) * G_ + gcol);
#pragma unroll
  for (int i = 0; i < 16; ++i)
    Uw[i] = Um[(size_t)(tk * 16 + i) * U_ + u0 + tc];

  // R5: time-invariant xA fold operands, hoisted to registers (pre-converted)
  float4 xAv[GB][4];
#pragma unroll
  for (int b = 0; b < GB; ++b) {
    const unsigned short* xap =
        xA + ((size_t)(bg * GB + b) * T_ + tk * 4) * G_ + gcol;
#pragma unroll
    for (int i = 0; i < 4; ++i) {
      ushort4 xv = *(const ushort4*)(xap + (size_t)i * G_);
      xAv[b][i] =
          make_float4(bf2f(xv.x), bf2f(xv.y), bf2f(xv.z), bf2f(xv.w));
    }
  }

  for (int idx = tid; idx < 16 * GB * T_; idx += NT) {
    int uc = idx >> 9;
    int b = (idx >> 7) & 3;
    int tt = idx & 127;
    attx_l[idx] = attxT[((size_t)(bg * GB + b) * U_ + u0 + uc) * T_ + tt];
  }
  for (int i = tid; i < GB * U_; i += NT) ((float*)h_s)[i] = 0.f;
  if (tid < GB * 16) ((float*)c_s)[tid] = 0.f;
  if (tid < 16) Vs_l[tid] = V[u0 + tid];
  unsigned* slots = bars + bg * (WPG * SLOTSTRIDE);
  unsigned epoch = 0;
  float* hpg = h_pub + (size_t)bg * GB * U_;
  float* spg = sp_g + (size_t)bg * GB * T_ * WPG;
  float xkv = 0.f;
  if (tid < 256) xkv = bf2f(xk[((size_t)(bg * GB + rb) * T_ + 0) * G_ + rcol]);
  __syncthreads();

  for (int t = 0; t < T_; ++t) {
    // ===== P1a: hU partial (h@Um own u-slice) -> scores -> sp publish
    float hUa[GB];
#pragma unroll
    for (int b = 0; b < GB; ++b) {
      float hu = 0.f;
      const float* hp = &h_s[b][tk * 16];
#pragma unroll
      for (int i = 0; i < 16; ++i) hu += hp[i] * Uw[i];
      hUa[b] = hu;
    }
#pragma unroll
    for (int b = 0; b < GB; ++b) {
      float hu = hUa[b];
      hu += __shfl_down(hu, 32);
      hu += __shfl_down(hu, 16);
      if (lane < 16) hUred[wv][b][lane] = hu;
    }
    __syncthreads();
    if (tid < 64) {
      int b = tid >> 4, u = tid & 15;
      float s = 0.f;
#pragma unroll
      for (int k = 0; k < 8; ++k) s += hUred[k][b][u];
      hU_s[b][u] = s;
    }
    __syncthreads();
    {  // score partials over own 16-u slice, all (b,t'); layout (b,t',w)
      float s = 0.f;
      const float* ax = &attx_l[bS * T_ + tS];
#pragma unroll
      for (int uc = 0; uc < 16; ++uc) {
        float e = tanh_fast(ax[uc * (GB * T_)] + hU_s[bS][uc]);
        s += e * Vs_l[uc];
      }
      pub_f32(fast, &spg[((size_t)bS * T_ + tS) * WPG + w], s);
    }
    grp_arrive(slots, w, ++epoch);  // B1 arrive

    // ===== B1 shadow: the big h@Rk matvec (independent of sp)
    float4 accR[GB];
#pragma unroll
    for (int b = 0; b < GB; ++b) {
      float4 a = make_float4(0.f, 0.f, 0.f, 0.f);
      const float* hp = &h_s[b][tk * 16];
#pragma unroll
      for (int i = 0; i < 16; ++i) {
        float hv = hp[i];
        a.x += hv * Rw[i].x;
        a.y += hv * Rw[i].y;
        a.z += hv * Rw[i].z;
        a.w += hv * Rw[i].w;
      }
      accR[b] = a;
    }
    grp_wait(fast, slots, epoch, &esc_s);  // B1 wait
    inv_l1(fast);                          // L1 clean before fast gathers

    // ===== P2: wide gather -> softmax (no max pass) -> fold -> LSTM
    {
      const float* spp = spg + ((size_t)bS * T_ + tS) * WPG;
      float4 a0, a1, a2, a3, a4, a5, a6, a7;
      gather32(fast, spp, a0, a1, a2, a3, a4, a5, a6, a7);
      float s = (((a0.x + a0.y) + (a0.z + a0.w)) + ((a1.x + a1.y) + (a1.z + a1.w))) +
                (((a2.x + a2.y) + (a2.z + a2.w)) + ((a3.x + a3.y) + (a3.z + a3.w))) +
                (((a4.x + a4.y) + (a4.z + a4.w)) + ((a5.x + a5.y) + (a5.z + a5.w))) +
                (((a6.x + a6.y) + (a6.z + a6.w)) + ((a7.x + a7.y) + (a7.z + a7.w)));
      float e = __expf(s);  // |s| <= ||V||_1 ~ 20: fp32-safe without shift
      sc_s[bS][tS] = e;
      float ls = e;  // lanes of this wave share bS
      for (int o = 32; o > 0; o >>= 1) ls += __shfl_down(ls, o);
      if (lane == 0) lsum_s[wv] = ls;
    }
    __syncthreads();
#pragma unroll
    for (int b = 0; b < GB; ++b) {
      float4 az = make_float4(0.f, 0.f, 0.f, 0.f);
#pragma unroll
      for (int i = 0; i < 4; ++i) {
        float al = sc_s[b][tk * 4 + i];
        az.x += al * xAv[b][i].x;
        az.y += al * xAv[b][i].y;
        az.z += al * xAv[b][i].z;
        az.w += al * xAv[b][i].w;
      }
      float il = 1.f / (lsum_s[2 * b] + lsum_s[2 * b + 1]);
      float4 comb;
      comb.x = accR[b].x + il * az.x;
      comb.y = accR[b].y + il * az.y;
      comb.z = accR[b].z + il * az.z;
      comb.w = accR[b].w + il * az.w;
      comb.x += __shfl_down(comb.x, 32);
      comb.y += __shfl_down(comb.y, 32);
      comb.z += __shfl_down(comb.z, 32);
      comb.w += __shfl_down(comb.w, 32);
      comb.x += __shfl_down(comb.x, 16);
      comb.y += __shfl_down(comb.y, 16);
      comb.z += __shfl_down(comb.z, 16);
      comb.w += __shfl_down(comb.w, 16);
      if (lane < 16) red2[wv][b][lane] = comb;
    }
    __syncthreads();
    if (tid < 256) {
      float gsum = xkv;
      const float* r2 = (const float*)red2;
#pragma unroll
      for (int k = 0; k < 8; ++k)
        gsum += r2[(((size_t)(k * GB + rb) * 17) + rtc) * 4 + rcomp];
      float gv = (rg == 2) ? tanh_fast(gsum)
                           : fminf(fmaxf(0.2f * gsum + 0.5f, 0.f), 1.f);
      act_s[rb][rg * 16 + rui] = gv;
    }
    __syncthreads();
    if (tid < 16) {
      int b = tid >> 2, uq = tid & 3;
      float4 hn4;
#pragma unroll
      for (int k2 = 0; k2 < 4; ++k2) {
        int ui = uq * 4 + k2;
        float i_ = act_s[b][ui];
        float f_ = act_s[b][16 + ui];
        float g_ = act_s[b][32 + ui];
        float o_ = act_s[b][48 + ui];
        float cn = f_ * c_s[b][ui] + i_ * g_;
        c_s[b][ui] = cn;
        ((float*)&hn4)[k2] = o_ * tanh_fast(cn);
      }
      int gb = bg * GB + b;
      store4_coh(fast, &hpg[(size_t)b * U_ + u0 + uq * 4], hn4);
      *(float4*)(out + ((size_t)gb * T_ + t) * U_ + u0 + uq * 4) = hn4;
    }
    grp_arrive(slots, w, ++epoch);  // B2 arrive

    // ===== B2 shadow: prefetch next step's xk
    int tn = (t + 1 < T_) ? t + 1 : t;
    float xkv_n = 0.f;
    if (tid < 256)
      xkv_n = bf2f(xk[((size_t)(bg * GB + rb) * T_ + tn) * G_ + rcol]);
    grp_wait(fast, slots, epoch, &esc_s);  // B2 wait
    inv_l1(fast);                          // L1 clean before h gather

    {
      float4 hv = load4_coh(fast, hpg + tid * 4);
      *(float4*)&((float*)h_s)[tid * 4] = hv;
    }
    xkv = xkv_n;
    __syncthreads();
  }
}

// ---------------------------------------------------------------------------
extern "C" void kernel_launch(void* const* d_in, const int* in_sizes, int n_in,
                              void* d_out, int out_size, void* d_ws,
                              size_t ws_size, hipStream_t stream) {
  (void)in_sizes;
  (void)n_in;
  (void)out_size;
  (void)ws_size;
  const float* x = (const float*)d_in[0];
  const float* Wk = (const float*)d_in[1];
  const float* Rk = (const float*)d_in[2];
  const float* Ak = (const float*)d_in[3];
  const float* Wa = (const float*)d_in[4];
  const float* Ua = (const float*)d_in[5];
  const float* Va = (const float*)d_in[6];
  const float* bias = (const float*)d_in[7];
  const float* ba = (const float*)d_in[8];
  float* out = (float*)d_out;

  char* ws = (char*)d_ws;
  unsigned short* xk_b = (unsigned short*)(ws);            // 16 MiB
  unsigned short* xA_b = (unsigned short*)(ws + 16777216); // 16 MiB
  float* attxT = (float*)(ws + 33554432);                  // 8 MiB
  float* h_pub = (float*)(ws + 41943040);                  // 64 KiB
  float* sp_g = (float*)(ws + 42008576);                   // 512 KiB
  unsigned* bars = (unsigned*)(ws + 42532864);             // 16 KiB

  gemm_bias_t<1><<<dim3(G_ / 64, (B_ * T_) / 64), 256, 0, stream>>>(
      x, Wk, bias, xk_b, G_);
  gemm_bias_t<1><<<dim3(G_ / 64, (B_ * T_) / 64), 256, 0, stream>>>(
      x, Ak, nullptr, xA_b, G_);
  gemm_bias_t<2><<<dim3(U_ / 64, (B_ * T_) / 64), 256, 0, stream>>>(
      x, Wa, ba, attxT, U_);
  (void)hipMemsetAsync(bars, 0, NGRP * WPG * SLOTSTRIDE * sizeof(unsigned),
                       stream);

  attlstm_rec<<<dim3(NGRP * WPG), dim3(NT), 0, stream>>>(
      xk_b, xA_b, attxT, Rk, Ua, Va, h_pub, sp_g, bars, out);
}

// Round 6
// 1754.743 us; speedup vs baseline: 1.3136x; 1.0094x over previous
//
#include <hip/hip_runtime.h>
#include <math.h>

#define B_ 32
#define T_ 128
#define D_ 512
#define U_ 512
#define G_ 2048   // 4U
#define NGRP 8    // batch groups
#define GB 4      // batches per group
#define WPG 32    // workgroups per group
#define NT 512    // threads per WG
#define GK 512    // K dim of precompute GEMMs
#define SLOTSTRIDE 16  // slot padding: 64B apart. word0=epoch, word8=XCD pub

__device__ __forceinline__ unsigned short f2bf(float v) {
  unsigned u = __float_as_uint(v);
  return (unsigned short)((u + 0x7FFFu + ((u >> 16) & 1u)) >> 16);
}
__device__ __forceinline__ float bf2f(unsigned short u) {
  return __uint_as_float(((unsigned)u) << 16);
}

// Device-coherence-point store (baseline path).
__device__ __forceinline__ void dev_store(float* p, float v) {
  __hip_atomic_store(p, v, __ATOMIC_RELAXED, __HIP_MEMORY_SCOPE_AGENT);
}

// Data publish: fast = sc0 (lands in the XCD's L2; same-XCD readers are
// coherent through that L2). slow = baseline agent-scope store.
__device__ __forceinline__ void pub_f32(bool fast, float* p, float v) {
  if (fast)
    asm volatile("global_store_dword %0, %1, off sc0" ::"v"(p), "v"(v)
                 : "memory");
  else
    dev_store(p, v);
}
__device__ __forceinline__ void store4_coh(bool fast, float* p, float4 v) {
  pub_f32(fast, p + 0, v.x);
  pub_f32(fast, p + 1, v.y);
  pub_f32(fast, p + 2, v.z);
  pub_f32(fast, p + 3, v.w);
}

// sc0 slot load for the fast poll (L2 latency). Escape path uses the
// baseline __hip_atomic_load, so a stale-L1 world cannot deadlock.
// NOTE (R4 post-mortem): NO buffer_inv inside the poll loop — per-iteration
// L1 invalidation nuked compute-phase locality and serialized the poll
// (1397 -> 2040 us). R3's structure (this one) is the verified optimum.
__device__ __forceinline__ unsigned ld_slot_sc0(const unsigned* p) {
  unsigned r;
  asm volatile(
      "global_load_dword %0, %1, off sc0\n\t"
      "s_waitcnt vmcnt(0)"
      : "=&v"(r)
      : "v"(p)
      : "memory");
  return r;
}

// Per-CU vector L1 invalidate before fast-mode data gathers (once per wait).
__device__ __forceinline__ void inv_l1(bool fast) {
  if (fast) asm volatile("buffer_inv sc0" ::: "memory");
}

// 32 contiguous floats as 8 pipelined dwordx4 loads + ONE waitcnt.
__device__ __forceinline__ void gather32(bool fast, const float* p, float4& a0,
                                         float4& a1, float4& a2, float4& a3,
                                         float4& a4, float4& a5, float4& a6,
                                         float4& a7) {
  if (fast) {
    asm volatile(
        "global_load_dwordx4 %0, %8, off sc0\n\t"
        "global_load_dwordx4 %1, %8, off offset:16 sc0\n\t"
        "global_load_dwordx4 %2, %8, off offset:32 sc0\n\t"
        "global_load_dwordx4 %3, %8, off offset:48 sc0\n\t"
        "global_load_dwordx4 %4, %8, off offset:64 sc0\n\t"
        "global_load_dwordx4 %5, %8, off offset:80 sc0\n\t"
        "global_load_dwordx4 %6, %8, off offset:96 sc0\n\t"
        "global_load_dwordx4 %7, %8, off offset:112 sc0\n\t"
        "s_waitcnt vmcnt(0)"
        : "=&v"(a0), "=&v"(a1), "=&v"(a2), "=&v"(a3), "=&v"(a4), "=&v"(a5),
          "=&v"(a6), "=&v"(a7)
        : "v"(p)
        : "memory");
  } else {
    asm volatile(
        "global_load_dwordx4 %0, %8, off sc0 sc1\n\t"
        "global_load_dwordx4 %1, %8, off offset:16 sc0 sc1\n\t"
        "global_load_dwordx4 %2, %8, off offset:32 sc0 sc1\n\t"
        "global_load_dwordx4 %3, %8, off offset:48 sc0 sc1\n\t"
        "global_load_dwordx4 %4, %8, off offset:64 sc0 sc1\n\t"
        "global_load_dwordx4 %5, %8, off offset:80 sc0 sc1\n\t"
        "global_load_dwordx4 %6, %8, off offset:96 sc0 sc1\n\t"
        "global_load_dwordx4 %7, %8, off offset:112 sc0 sc1\n\t"
        "s_waitcnt vmcnt(0)"
        : "=&v"(a0), "=&v"(a1), "=&v"(a2), "=&v"(a3), "=&v"(a4), "=&v"(a5),
          "=&v"(a6), "=&v"(a7)
        : "v"(p)
        : "memory");
  }
}

__device__ __forceinline__ float4 load4_coh(bool fast, const float* p) {
  float4 r;
  if (fast)
    asm volatile(
        "global_load_dwordx4 %0, %1, off sc0\n\t"
        "s_waitcnt vmcnt(0)"
        : "=&v"(r)
        : "v"(p)
        : "memory");
  else
    asm volatile(
        "global_load_dwordx4 %0, %1, off sc0 sc1\n\t"
        "s_waitcnt vmcnt(0)"
        : "=&v"(r)
        : "v"(p)
        : "memory");
  return r;
}

// ---------------------------------------------------------------------------
// Precompute GEMM: C[M,N] = A[M,512] @ W[512,N] + bias  (bias may be null)
// MODE 1: bf16 row-major; MODE 2: fp32 (B,U,T)-transposed
// ---------------------------------------------------------------------------
template <int MODE>
__global__ __launch_bounds__(256) void gemm_bias_t(const float* __restrict__ A,
                                                   const float* __restrict__ W,
                                                   const float* __restrict__ bias,
                                                   void* __restrict__ Cout, int N) {
  __shared__ float As[16][68];
  __shared__ float Ws[16][64];
  const int tid = threadIdx.x;
  const int rowbase = blockIdx.y * 64;
  const int colbase = blockIdx.x * 64;
  const int ty = tid >> 4, tx = tid & 15;
  const int ar = tid >> 2, ak = (tid & 3) << 2;
  const int wk = tid >> 4, wc = (tid & 15) << 2;
  float acc[4][4] = {{0.f, 0.f, 0.f, 0.f}};
  for (int k0 = 0; k0 < GK; k0 += 16) {
    float4 av = *(const float4*)(A + (size_t)(rowbase + ar) * GK + k0 + ak);
    float4 wv = *(const float4*)(W + (size_t)(k0 + wk) * N + colbase + wc);
    __syncthreads();
    As[ak + 0][ar] = av.x;
    As[ak + 1][ar] = av.y;
    As[ak + 2][ar] = av.z;
    As[ak + 3][ar] = av.w;
    *(float4*)(&Ws[wk][wc]) = wv;
    __syncthreads();
#pragma unroll
    for (int kk = 0; kk < 16; ++kk) {
      float4 a = *(const float4*)(&As[kk][ty << 2]);
      float4 wv2 = *(const float4*)(&Ws[kk][tx << 2]);
      float a4[4] = {a.x, a.y, a.z, a.w};
      float w4[4] = {wv2.x, wv2.y, wv2.z, wv2.w};
#pragma unroll
      for (int i = 0; i < 4; ++i)
#pragma unroll
        for (int jj = 0; jj < 4; ++jj) acc[i][jj] += a4[i] * w4[jj];
    }
  }
  float4 bv = bias ? *(const float4*)(bias + colbase + (tx << 2))
                   : make_float4(0.f, 0.f, 0.f, 0.f);
#pragma unroll
  for (int i = 0; i < 4; ++i) {
    const int row = rowbase + (ty << 2) + i;
    float o[4] = {acc[i][0] + bv.x, acc[i][1] + bv.y, acc[i][2] + bv.z,
                  acc[i][3] + bv.w};
    if (MODE == 1) {
      ushort4 ob;
      ob.x = f2bf(o[0]); ob.y = f2bf(o[1]); ob.z = f2bf(o[2]); ob.w = f2bf(o[3]);
      *(ushort4*)((unsigned short*)Cout + (size_t)row * N + colbase + (tx << 2)) = ob;
    } else {
      const int b = row >> 7, tt = row & 127;
#pragma unroll
      for (int jj = 0; jj < 4; ++jj) {
        int u = colbase + (tx << 2) + jj;
        ((float*)Cout)[((size_t)b * U_ + u) * T_ + tt] = o[jj];
      }
    }
  }
}

__device__ __forceinline__ float tanh_fast(float x) {
  return 1.f - 2.f / (__expf(2.f * x) + 1.f);
}

// Split-phase RMW-free barrier (R3-verified structure). Arrive: explicit
// vmcnt(0) (inline-asm data stores are invisible to the compiler's barrier
// lowering) + syncthreads + own padded slot store (agent scope). Wait:
// parallel 32-slot poll; fast mode polls with sc0 (L2) and sticky-escapes
// to the agent-scope poll after 512 tries -> deadlock-impossible in any
// coherence interpretation. Independent work goes between arrive and wait.
__device__ __forceinline__ void grp_arrive(unsigned* slots, int w,
                                           unsigned epoch) {
  asm volatile("s_waitcnt vmcnt(0)" ::: "memory");
  __syncthreads();
  if (threadIdx.x == 0)
    __hip_atomic_store(&slots[w * SLOTSTRIDE], epoch, __ATOMIC_RELAXED,
                       __HIP_MEMORY_SCOPE_AGENT);
}
__device__ __forceinline__ void grp_wait(bool fast, const unsigned* slots,
                                         unsigned epoch, int* esc_flag) {
  if (threadIdx.x < 64) {
    bool esc = !fast || (*esc_flag != 0);
    int tries = 0;
    bool done = false;
    do {
      unsigned v;
      if (threadIdx.x < WPG) {
        v = esc ? __hip_atomic_load(&slots[threadIdx.x * SLOTSTRIDE],
                                    __ATOMIC_RELAXED, __HIP_MEMORY_SCOPE_AGENT)
                : ld_slot_sc0(&slots[threadIdx.x * SLOTSTRIDE]);
      } else {
        v = epoch;
      }
      done = __all(v >= epoch);
      if (!done && !esc && ++tries > 512) {
        esc = true;
        if (threadIdx.x == 0) *esc_flag = 1;
      }
    } while (!done);
  }
  __syncthreads();
}

// ---------------------------------------------------------------------------
// Weight-stationary recurrence, split-phase barriers. 8 groups x 32 WGs x
// 512 threads. B1 wait hidden under the h@Rk matvec; B2 wait hides the xk
// prefetch. sp layout (b,t,w): reader's 32 partials = one 128B block.
// Phase 0: each WG publishes HW_REG_XCC_ID into word 8 of its own barrier
// slot; if every XCD holds exactly 32 WGs, groups remap to bg=xcd /
// w=rank-in-xcd so all group-internal bulk traffic (sp, h) stays in that
// XCD's shared L2 (sc0) instead of the device coherence point. Fallback ->
// baseline path. R3 verified: fast path engages (WRITE_SIZE 567->86 MB).
// R6: __launch_bounds__(NT, 2) — grid is exactly 1 WG/CU (2 waves/EU), so
// targeting the default 4-waves/EU occupancy only strangles the register
// allocator (R5: VGPR stuck at 128, xAv hoist silently sunk back into the
// loop). min-2-waves/EU raises the VGPR ceiling to 256 so the
// time-invariant xA fold operands (float4 xAv[GB][4], 64 VGPRs) actually
// live in registers across the T-loop.
// ---------------------------------------------------------------------------
__global__ __launch_bounds__(NT, 2) void attlstm_rec(
    const unsigned short* __restrict__ xk,  // (B,T,4U) bf16
    const unsigned short* __restrict__ xA,  // (B,T,4U) bf16
    const float* __restrict__ attxT,        // (B,U,T) fp32
    const float* __restrict__ Rk,           // (U,4U)
    const float* __restrict__ Um,           // (U,U)
    const float* __restrict__ V,            // (U)
    float* __restrict__ h_pub,              // (NGRP,GB,U)
    float* __restrict__ sp_g,               // (NGRP,GB,T,WPG)
    unsigned* __restrict__ bars,            // (NGRP,WPG*SLOTSTRIDE)
    float* __restrict__ out) {              // (B,T,U)
  const int tid = threadIdx.x;

  // ===== Phase 0 (one-time): XCD placement discovery & group remap =====
  __shared__ unsigned char xcd_l[256];
  __shared__ int map_s[3];
  __shared__ int esc_s;
  unsigned myxcd;
  asm volatile("s_getreg_b32 %0, hwreg(HW_REG_XCC_ID)" : "=s"(myxcd));
  if (tid == 0)
    __hip_atomic_store(&bars[(unsigned)blockIdx.x * SLOTSTRIDE + 8],
                       (myxcd & 0xffu) + 1u, __ATOMIC_RELAXED,
                       __HIP_MEMORY_SCOPE_AGENT);
  if (tid < 256) {
    unsigned v;
    do {  // same co-residency requirement as the baseline's own barriers
      v = __hip_atomic_load(&bars[(unsigned)tid * SLOTSTRIDE + 8],
                            __ATOMIC_RELAXED, __HIP_MEMORY_SCOPE_AGENT);
    } while (v == 0u);
    xcd_l[tid] = (unsigned char)(v - 1u);
  }
  if (tid == 0) esc_s = 0;
  __syncthreads();
  if (tid == 0) {
    int cnt[8] = {0, 0, 0, 0, 0, 0, 0, 0};
    int rank = 0;
    bool ok = true;
    const int myb = (int)blockIdx.x;
    const int myx = (int)(unsigned)xcd_l[myb];
    for (int i = 0; i < 256; ++i) {
      int xc = (int)(unsigned)xcd_l[i];
      if (xc > 7) { ok = false; break; }
      cnt[xc]++;
      if (i < myb && xc == myx) rank++;
    }
    if (ok)
      for (int i = 0; i < 8; ++i) ok &= (cnt[i] == 32);
    map_s[0] = ok ? myx : (myb & 7);
    map_s[1] = ok ? rank : (myb >> 3);
    map_s[2] = ok ? 1 : 0;
  }
  __syncthreads();
  const int bg = map_s[0];
  const int w = map_s[1];
  const bool fast = (map_s[2] != 0);

  const int u0 = w * 16;
  const int tk = tid >> 4;  // 0..31 (K-chunk of 16)
  const int tc = tid & 15;  // col-quad id
  const int gcol = (tc >> 2) * U_ + u0 + (tc & 3) * 4;
  const int wv = tid >> 6;
  const int lane = tid & 63;
  const int bS = tid >> 7;
  const int tS = tid & 127;
  const int rb = tid >> 6;  // reducer role (tid<256)
  const int rc = tid & 63;
  const int rtc = rc >> 2, rcomp = rc & 3;
  const int rg = rtc >> 2;
  const int rui = ((rtc & 3) << 2) | rcomp;
  const int rcol = rg * U_ + u0 + rui;

  __shared__ float attx_l[16 * GB * T_];  // 32 KB
  __shared__ float h_s[GB][U_];           // 8 KB
  __shared__ float4 red2[8][GB][17];
  __shared__ float hUred[8][GB][17];
  __shared__ float sc_s[GB][T_];
  __shared__ float hU_s[GB][16];
  __shared__ float act_s[GB][64];
  __shared__ float c_s[GB][16];
  __shared__ float lsum_s[8];
  __shared__ float Vs_l[16];

  float4 Rw[16];
  float Uw[16];
#pragma unroll
  for (int i = 0; i < 16; ++i)
    Rw[i] = *(const float4*)(Rk + (size_t)(tk * 16 + i) * G_ + gcol);
#pragma unroll
  for (int i = 0; i < 16; ++i)
    Uw[i] = Um[(size_t)(tk * 16 + i) * U_ + u0 + tc];

  // Time-invariant xA fold operands, hoisted to registers (pre-converted)
  float4 xAv[GB][4];
#pragma unroll
  for (int b = 0; b < GB; ++b) {
    const unsigned short* xap =
        xA + ((size_t)(bg * GB + b) * T_ + tk * 4) * G_ + gcol;
#pragma unroll
    for (int i = 0; i < 4; ++i) {
      ushort4 xv = *(const ushort4*)(xap + (size_t)i * G_);
      xAv[b][i] =
          make_float4(bf2f(xv.x), bf2f(xv.y), bf2f(xv.z), bf2f(xv.w));
    }
  }

  for (int idx = tid; idx < 16 * GB * T_; idx += NT) {
    int uc = idx >> 9;
    int b = (idx >> 7) & 3;
    int tt = idx & 127;
    attx_l[idx] = attxT[((size_t)(bg * GB + b) * U_ + u0 + uc) * T_ + tt];
  }
  for (int i = tid; i < GB * U_; i += NT) ((float*)h_s)[i] = 0.f;
  if (tid < GB * 16) ((float*)c_s)[tid] = 0.f;
  if (tid < 16) Vs_l[tid] = V[u0 + tid];
  unsigned* slots = bars + bg * (WPG * SLOTSTRIDE);
  unsigned epoch = 0;
  float* hpg = h_pub + (size_t)bg * GB * U_;
  float* spg = sp_g + (size_t)bg * GB * T_ * WPG;
  float xkv = 0.f;
  if (tid < 256) xkv = bf2f(xk[((size_t)(bg * GB + rb) * T_ + 0) * G_ + rcol]);
  __syncthreads();

  for (int t = 0; t < T_; ++t) {
    // ===== P1a: hU partial (h@Um own u-slice) -> scores -> sp publish
    float hUa[GB];
#pragma unroll
    for (int b = 0; b < GB; ++b) {
      float hu = 0.f;
      const float* hp = &h_s[b][tk * 16];
#pragma unroll
      for (int i = 0; i < 16; ++i) hu += hp[i] * Uw[i];
      hUa[b] = hu;
    }
#pragma unroll
    for (int b = 0; b < GB; ++b) {
      float hu = hUa[b];
      hu += __shfl_down(hu, 32);
      hu += __shfl_down(hu, 16);
      if (lane < 16) hUred[wv][b][lane] = hu;
    }
    __syncthreads();
    if (tid < 64) {
      int b = tid >> 4, u = tid & 15;
      float s = 0.f;
#pragma unroll
      for (int k = 0; k < 8; ++k) s += hUred[k][b][u];
      hU_s[b][u] = s;
    }
    __syncthreads();
    {  // score partials over own 16-u slice, all (b,t'); layout (b,t',w)
      float s = 0.f;
      const float* ax = &attx_l[bS * T_ + tS];
#pragma unroll
      for (int uc = 0; uc < 16; ++uc) {
        float e = tanh_fast(ax[uc * (GB * T_)] + hU_s[bS][uc]);
        s += e * Vs_l[uc];
      }
      pub_f32(fast, &spg[((size_t)bS * T_ + tS) * WPG + w], s);
    }
    grp_arrive(slots, w, ++epoch);  // B1 arrive

    // ===== B1 shadow: the big h@Rk matvec (independent of sp)
    float4 accR[GB];
#pragma unroll
    for (int b = 0; b < GB; ++b) {
      float4 a = make_float4(0.f, 0.f, 0.f, 0.f);
      const float* hp = &h_s[b][tk * 16];
#pragma unroll
      for (int i = 0; i < 16; ++i) {
        float hv = hp[i];
        a.x += hv * Rw[i].x;
        a.y += hv * Rw[i].y;
        a.z += hv * Rw[i].z;
        a.w += hv * Rw[i].w;
      }
      accR[b] = a;
    }
    grp_wait(fast, slots, epoch, &esc_s);  // B1 wait
    inv_l1(fast);                          // L1 clean before fast gathers

    // ===== P2: wide gather -> softmax (no max pass) -> fold -> LSTM
    {
      const float* spp = spg + ((size_t)bS * T_ + tS) * WPG;
      float4 a0, a1, a2, a3, a4, a5, a6, a7;
      gather32(fast, spp, a0, a1, a2, a3, a4, a5, a6, a7);
      float s = (((a0.x + a0.y) + (a0.z + a0.w)) + ((a1.x + a1.y) + (a1.z + a1.w))) +
                (((a2.x + a2.y) + (a2.z + a2.w)) + ((a3.x + a3.y) + (a3.z + a3.w))) +
                (((a4.x + a4.y) + (a4.z + a4.w)) + ((a5.x + a5.y) + (a5.z + a5.w))) +
                (((a6.x + a6.y) + (a6.z + a6.w)) + ((a7.x + a7.y) + (a7.z + a7.w)));
      float e = __expf(s);  // |s| <= ||V||_1 ~ 20: fp32-safe without shift
      sc_s[bS][tS] = e;
      float ls = e;  // lanes of this wave share bS
      for (int o = 32; o > 0; o >>= 1) ls += __shfl_down(ls, o);
      if (lane == 0) lsum_s[wv] = ls;
    }
    __syncthreads();
#pragma unroll
    for (int b = 0; b < GB; ++b) {
      float4 az = make_float4(0.f, 0.f, 0.f, 0.f);
#pragma unroll
      for (int i = 0; i < 4; ++i) {
        float al = sc_s[b][tk * 4 + i];
        az.x += al * xAv[b][i].x;
        az.y += al * xAv[b][i].y;
        az.z += al * xAv[b][i].z;
        az.w += al * xAv[b][i].w;
      }
      float il = 1.f / (lsum_s[2 * b] + lsum_s[2 * b + 1]);
      float4 comb;
      comb.x = accR[b].x + il * az.x;
      comb.y = accR[b].y + il * az.y;
      comb.z = accR[b].z + il * az.z;
      comb.w = accR[b].w + il * az.w;
      comb.x += __shfl_down(comb.x, 32);
      comb.y += __shfl_down(comb.y, 32);
      comb.z += __shfl_down(comb.z, 32);
      comb.w += __shfl_down(comb.w, 32);
      comb.x += __shfl_down(comb.x, 16);
      comb.y += __shfl_down(comb.y, 16);
      comb.z += __shfl_down(comb.z, 16);
      comb.w += __shfl_down(comb.w, 16);
      if (lane < 16) red2[wv][b][lane] = comb;
    }
    __syncthreads();
    if (tid < 256) {
      float gsum = xkv;
      const float* r2 = (const float*)red2;
#pragma unroll
      for (int k = 0; k < 8; ++k)
        gsum += r2[(((size_t)(k * GB + rb) * 17) + rtc) * 4 + rcomp];
      float gv = (rg == 2) ? tanh_fast(gsum)
                           : fminf(fmaxf(0.2f * gsum + 0.5f, 0.f), 1.f);
      act_s[rb][rg * 16 + rui] = gv;
    }
    __syncthreads();
    if (tid < 16) {
      int b = tid >> 2, uq = tid & 3;
      float4 hn4;
#pragma unroll
      for (int k2 = 0; k2 < 4; ++k2) {
        int ui = uq * 4 + k2;
        float i_ = act_s[b][ui];
        float f_ = act_s[b][16 + ui];
        float g_ = act_s[b][32 + ui];
        float o_ = act_s[b][48 + ui];
        float cn = f_ * c_s[b][ui] + i_ * g_;
        c_s[b][ui] = cn;
        ((float*)&hn4)[k2] = o_ * tanh_fast(cn);
      }
      int gb = bg * GB + b;
      store4_coh(fast, &hpg[(size_t)b * U_ + u0 + uq * 4], hn4);
      *(float4*)(out + ((size_t)gb * T_ + t) * U_ + u0 + uq * 4) = hn4;
    }
    grp_arrive(slots, w, ++epoch);  // B2 arrive

    // ===== B2 shadow: prefetch next step's xk
    int tn = (t + 1 < T_) ? t + 1 : t;
    float xkv_n = 0.f;
    if (tid < 256)
      xkv_n = bf2f(xk[((size_t)(bg * GB + rb) * T_ + tn) * G_ + rcol]);
    grp_wait(fast, slots, epoch, &esc_s);  // B2 wait
    inv_l1(fast);                          // L1 clean before h gather

    {
      float4 hv = load4_coh(fast, hpg + tid * 4);
      *(float4*)&((float*)h_s)[tid * 4] = hv;
    }
    xkv = xkv_n;
    __syncthreads();
  }
}

// ---------------------------------------------------------------------------
extern "C" void kernel_launch(void* const* d_in, const int* in_sizes, int n_in,
                              void* d_out, int out_size, void* d_ws,
                              size_t ws_size, hipStream_t stream) {
  (void)in_sizes;
  (void)n_in;
  (void)out_size;
  (void)ws_size;
  const float* x = (const float*)d_in[0];
  const float* Wk = (const float*)d_in[1];
  const float* Rk = (const float*)d_in[2];
  const float* Ak = (const float*)d_in[3];
  const float* Wa = (const float*)d_in[4];
  const float* Ua = (const float*)d_in[5];
  const float* Va = (const float*)d_in[6];
  const float* bias = (const float*)d_in[7];
  const float* ba = (const float*)d_in[8];
  float* out = (float*)d_out;

  char* ws = (char*)d_ws;
  unsigned short* xk_b = (unsigned short*)(ws);            // 16 MiB
  unsigned short* xA_b = (unsigned short*)(ws + 16777216); // 16 MiB
  float* attxT = (float*)(ws + 33554432);                  // 8 MiB
  float* h_pub = (float*)(ws + 41943040);                  // 64 KiB
  float* sp_g = (float*)(ws + 42008576);                   // 512 KiB
  unsigned* bars = (unsigned*)(ws + 42532864);             // 16 KiB

  gemm_bias_t<1><<<dim3(G_ / 64, (B_ * T_) / 64), 256, 0, stream>>>(
      x, Wk, bias, xk_b, G_);
  gemm_bias_t<1><<<dim3(G_ / 64, (B_ * T_) / 64), 256, 0, stream>>>(
      x, Ak, nullptr, xA_b, G_);
  gemm_bias_t<2><<<dim3(U_ / 64, (B_ * T_) / 64), 256, 0, stream>>>(
      x, Wa, ba, attxT, U_);
  (void)hipMemsetAsync(bars, 0, NGRP * WPG * SLOTSTRIDE * sizeof(unsigned),
                       stream);

  attlstm_rec<<<dim3(NGRP * WPG), dim3(NT), 0, stream>>>(
      xk_b, xA_b, attxT, Rk, Ua, Va, h_pub, sp_g, bars, out);
}

// Round 7
// 1667.170 us; speedup vs baseline: 1.3826x; 1.0525x over previous
//
#include <hip/hip_runtime.h>
#include <math.h>

#define B_ 32
#define T_ 128
#define D_ 512
#define U_ 512
#define G_ 2048   // 4U
#define NGRP 8    // batch groups
#define GB 4      // batches per group
#define WPG 32    // workgroups per group
#define NT 512    // threads per WG
#define GK 512    // K dim of precompute GEMMs
#define SLOTSTRIDE 16  // slot padding: 64B apart. word0=fast epoch,
                       // word4=agent mirror epoch, word8=phase0 XCD publish

__device__ __forceinline__ unsigned short f2bf(float v) {
  unsigned u = __float_as_uint(v);
  return (unsigned short)((u + 0x7FFFu + ((u >> 16) & 1u)) >> 16);
}
__device__ __forceinline__ float bf2f(unsigned short u) {
  return __uint_as_float(((unsigned)u) << 16);
}

// Device-coherence-point store (baseline path).
__device__ __forceinline__ void dev_store(float* p, float v) {
  __hip_atomic_store(p, v, __ATOMIC_RELAXED, __HIP_MEMORY_SCOPE_AGENT);
}

// Data publish: fast = sc0 (lands in the XCD's L2; same-XCD readers are
// coherent through that L2). slow = baseline agent-scope store.
__device__ __forceinline__ void pub_f32(bool fast, float* p, float v) {
  if (fast)
    asm volatile("global_store_dword %0, %1, off sc0" ::"v"(p), "v"(v)
                 : "memory");
  else
    dev_store(p, v);
}
__device__ __forceinline__ void store4_coh(bool fast, float* p, float4 v) {
  pub_f32(fast, p + 0, v.x);
  pub_f32(fast, p + 1, v.y);
  pub_f32(fast, p + 2, v.z);
  pub_f32(fast, p + 3, v.w);
}

// sc0 slot load for the fast poll (L2 latency). NO buffer_inv here (R4
// post-mortem: inv-per-iteration nuked L1 locality + serialized the poll,
// 1397 -> 2040 us). R3 evidence: sc0 poll loads DO observe fresh L2 epochs
// (the 512-try escape never fires on the steady path).
__device__ __forceinline__ unsigned ld_slot_sc0(const unsigned* p) {
  unsigned r;
  asm volatile(
      "global_load_dword %0, %1, off sc0\n\t"
      "s_waitcnt vmcnt(0)"
      : "=&v"(r)
      : "v"(p)
      : "memory");
  return r;
}

// Per-CU vector L1 invalidate before fast-mode data gathers (once per wait).
__device__ __forceinline__ void inv_l1(bool fast) {
  if (fast) asm volatile("buffer_inv sc0" ::: "memory");
}

// 32 contiguous floats as 8 pipelined dwordx4 loads + ONE waitcnt.
__device__ __forceinline__ void gather32(bool fast, const float* p, float4& a0,
                                         float4& a1, float4& a2, float4& a3,
                                         float4& a4, float4& a5, float4& a6,
                                         float4& a7) {
  if (fast) {
    asm volatile(
        "global_load_dwordx4 %0, %8, off sc0\n\t"
        "global_load_dwordx4 %1, %8, off offset:16 sc0\n\t"
        "global_load_dwordx4 %2, %8, off offset:32 sc0\n\t"
        "global_load_dwordx4 %3, %8, off offset:48 sc0\n\t"
        "global_load_dwordx4 %4, %8, off offset:64 sc0\n\t"
        "global_load_dwordx4 %5, %8, off offset:80 sc0\n\t"
        "global_load_dwordx4 %6, %8, off offset:96 sc0\n\t"
        "global_load_dwordx4 %7, %8, off offset:112 sc0\n\t"
        "s_waitcnt vmcnt(0)"
        : "=&v"(a0), "=&v"(a1), "=&v"(a2), "=&v"(a3), "=&v"(a4), "=&v"(a5),
          "=&v"(a6), "=&v"(a7)
        : "v"(p)
        : "memory");
  } else {
    asm volatile(
        "global_load_dwordx4 %0, %8, off sc0 sc1\n\t"
        "global_load_dwordx4 %1, %8, off offset:16 sc0 sc1\n\t"
        "global_load_dwordx4 %2, %8, off offset:32 sc0 sc1\n\t"
        "global_load_dwordx4 %3, %8, off offset:48 sc0 sc1\n\t"
        "global_load_dwordx4 %4, %8, off offset:64 sc0 sc1\n\t"
        "global_load_dwordx4 %5, %8, off offset:80 sc0 sc1\n\t"
        "global_load_dwordx4 %6, %8, off offset:96 sc0 sc1\n\t"
        "global_load_dwordx4 %7, %8, off offset:112 sc0 sc1\n\t"
        "s_waitcnt vmcnt(0)"
        : "=&v"(a0), "=&v"(a1), "=&v"(a2), "=&v"(a3), "=&v"(a4), "=&v"(a5),
          "=&v"(a6), "=&v"(a7)
        : "v"(p)
        : "memory");
  }
}

__device__ __forceinline__ float4 load4_coh(bool fast, const float* p) {
  float4 r;
  if (fast)
    asm volatile(
        "global_load_dwordx4 %0, %1, off sc0\n\t"
        "s_waitcnt vmcnt(0)"
        : "=&v"(r)
        : "v"(p)
        : "memory");
  else
    asm volatile(
        "global_load_dwordx4 %0, %1, off sc0 sc1\n\t"
        "s_waitcnt vmcnt(0)"
        : "=&v"(r)
        : "v"(p)
        : "memory");
  return r;
}

// ---------------------------------------------------------------------------
// Precompute GEMM: C[M,N] = A[M,512] @ W[512,N] + bias  (bias may be null)
// MODE 1: bf16 row-major; MODE 2: fp32 (B,U,T)-transposed
// ---------------------------------------------------------------------------
template <int MODE>
__global__ __launch_bounds__(256) void gemm_bias_t(const float* __restrict__ A,
                                                   const float* __restrict__ W,
                                                   const float* __restrict__ bias,
                                                   void* __restrict__ Cout, int N) {
  __shared__ float As[16][68];
  __shared__ float Ws[16][64];
  const int tid = threadIdx.x;
  const int rowbase = blockIdx.y * 64;
  const int colbase = blockIdx.x * 64;
  const int ty = tid >> 4, tx = tid & 15;
  const int ar = tid >> 2, ak = (tid & 3) << 2;
  const int wk = tid >> 4, wc = (tid & 15) << 2;
  float acc[4][4] = {{0.f, 0.f, 0.f, 0.f}};
  for (int k0 = 0; k0 < GK; k0 += 16) {
    float4 av = *(const float4*)(A + (size_t)(rowbase + ar) * GK + k0 + ak);
    float4 wv = *(const float4*)(W + (size_t)(k0 + wk) * N + colbase + wc);
    __syncthreads();
    As[ak + 0][ar] = av.x;
    As[ak + 1][ar] = av.y;
    As[ak + 2][ar] = av.z;
    As[ak + 3][ar] = av.w;
    *(float4*)(&Ws[wk][wc]) = wv;
    __syncthreads();
#pragma unroll
    for (int kk = 0; kk < 16; ++kk) {
      float4 a = *(const float4*)(&As[kk][ty << 2]);
      float4 wv2 = *(const float4*)(&Ws[kk][tx << 2]);
      float a4[4] = {a.x, a.y, a.z, a.w};
      float w4[4] = {wv2.x, wv2.y, wv2.z, wv2.w};
#pragma unroll
      for (int i = 0; i < 4; ++i)
#pragma unroll
        for (int jj = 0; jj < 4; ++jj) acc[i][jj] += a4[i] * w4[jj];
    }
  }
  float4 bv = bias ? *(const float4*)(bias + colbase + (tx << 2))
                   : make_float4(0.f, 0.f, 0.f, 0.f);
#pragma unroll
  for (int i = 0; i < 4; ++i) {
    const int row = rowbase + (ty << 2) + i;
    float o[4] = {acc[i][0] + bv.x, acc[i][1] + bv.y, acc[i][2] + bv.z,
                  acc[i][3] + bv.w};
    if (MODE == 1) {
      ushort4 ob;
      ob.x = f2bf(o[0]); ob.y = f2bf(o[1]); ob.z = f2bf(o[2]); ob.w = f2bf(o[3]);
      *(ushort4*)((unsigned short*)Cout + (size_t)row * N + colbase + (tx << 2)) = ob;
    } else {
      const int b = row >> 7, tt = row & 127;
#pragma unroll
      for (int jj = 0; jj < 4; ++jj) {
        int u = colbase + (tx << 2) + jj;
        ((float*)Cout)[((size_t)b * U_ + u) * T_ + tt] = o[jj];
      }
    }
  }
}

__device__ __forceinline__ float tanh_fast(float x) {
  return 1.f - 2.f / (__expf(2.f * x) + 1.f);
}

// Split-phase RMW-free barrier. Arrive: explicit vmcnt(0) (inline-asm data
// stores are invisible to the compiler's barrier lowering) + syncthreads +
// own padded slot store. R7: fast mode arrives with an sc0 slot store
// (XCD-L2-visible at L2 latency, not MALL) PLUS an agent-scope mirror at
// word 4 (deadlock safety net). Wait: R3's verbatim poll — sc0 loads (no
// inv), sticky-escape to agent polls of the mirror after 512 tries ->
// correct under any coherence interpretation.
__device__ __forceinline__ void grp_arrive(bool fast, unsigned* slots, int w,
                                           unsigned epoch) {
  asm volatile("s_waitcnt vmcnt(0)" ::: "memory");
  __syncthreads();
  if (threadIdx.x == 0) {
    if (fast) {
      asm volatile("global_store_dword %0, %1, off sc0" ::"v"(
                       &slots[w * SLOTSTRIDE]),
                   "v"(epoch)
                   : "memory");
      __hip_atomic_store(&slots[w * SLOTSTRIDE + 4], epoch, __ATOMIC_RELAXED,
                         __HIP_MEMORY_SCOPE_AGENT);
    } else {
      __hip_atomic_store(&slots[w * SLOTSTRIDE], epoch, __ATOMIC_RELAXED,
                         __HIP_MEMORY_SCOPE_AGENT);
    }
  }
}
__device__ __forceinline__ void grp_wait(bool fast, const unsigned* slots,
                                         unsigned epoch, int* esc_flag) {
  if (threadIdx.x < 64) {
    bool esc = !fast || (*esc_flag != 0);
    int tries = 0;
    bool done = false;
    const unsigned* pf = &slots[threadIdx.x * SLOTSTRIDE];
    const unsigned* pe = &slots[threadIdx.x * SLOTSTRIDE + (fast ? 4 : 0)];
    do {
      unsigned v;
      if (threadIdx.x < WPG) {
        v = esc ? __hip_atomic_load(pe, __ATOMIC_RELAXED,
                                    __HIP_MEMORY_SCOPE_AGENT)
                : ld_slot_sc0(pf);
      } else {
        v = epoch;
      }
      done = __all(v >= epoch);
      if (!done && !esc && ++tries > 512) {
        esc = true;
        if (threadIdx.x == 0) *esc_flag = 1;
      }
    } while (!done);
  }
  __syncthreads();
}

// ---------------------------------------------------------------------------
// Weight-stationary recurrence, split-phase barriers. 8 groups x 32 WGs x
// 512 threads. B1 wait hidden under the h@Rk matvec; B2 wait hides the xk
// prefetch. sp layout (b,t,w): reader's 32 partials = one 128B block.
// Phase 0: each WG publishes HW_REG_XCC_ID into word 8 of its own barrier
// slot; if every XCD holds exactly 32 WGs, groups remap to bg=xcd /
// w=rank-in-xcd so all group-internal bulk traffic (sp, h) stays in that
// XCD's shared L2 (sc0) instead of the device coherence point. Fallback ->
// baseline path. R3 verified: fast path engages (WRITE_SIZE 567->86 MB).
// R7 = exact R3 structure (R5/R6's xAv hoist refuted: compiler remats the
// loads; steady 1443 vs 1397) + two isolated deltas:
//   (a) sc0 fast-arrive w/ agent mirror (R4's idea minus its inv-poison),
//   (b) LSTM tail widened tid<16 -> tid<64 (1 u/lane, same math).
// ---------------------------------------------------------------------------
__global__ __launch_bounds__(NT) void attlstm_rec(
    const unsigned short* __restrict__ xk,  // (B,T,4U) bf16
    const unsigned short* __restrict__ xA,  // (B,T,4U) bf16
    const float* __restrict__ attxT,        // (B,U,T) fp32
    const float* __restrict__ Rk,           // (U,4U)
    const float* __restrict__ Um,           // (U,U)
    const float* __restrict__ V,            // (U)
    float* __restrict__ h_pub,              // (NGRP,GB,U)
    float* __restrict__ sp_g,               // (NGRP,GB,T,WPG)
    unsigned* __restrict__ bars,            // (NGRP,WPG*SLOTSTRIDE)
    float* __restrict__ out) {              // (B,T,U)
  const int tid = threadIdx.x;

  // ===== Phase 0 (one-time): XCD placement discovery & group remap =====
  __shared__ unsigned char xcd_l[256];
  __shared__ int map_s[3];
  __shared__ int esc_s;
  unsigned myxcd;
  asm volatile("s_getreg_b32 %0, hwreg(HW_REG_XCC_ID)" : "=s"(myxcd));
  if (tid == 0)
    __hip_atomic_store(&bars[(unsigned)blockIdx.x * SLOTSTRIDE + 8],
                       (myxcd & 0xffu) + 1u, __ATOMIC_RELAXED,
                       __HIP_MEMORY_SCOPE_AGENT);
  if (tid < 256) {
    unsigned v;
    do {  // same co-residency requirement as the baseline's own barriers
      v = __hip_atomic_load(&bars[(unsigned)tid * SLOTSTRIDE + 8],
                            __ATOMIC_RELAXED, __HIP_MEMORY_SCOPE_AGENT);
    } while (v == 0u);
    xcd_l[tid] = (unsigned char)(v - 1u);
  }
  if (tid == 0) esc_s = 0;
  __syncthreads();
  if (tid == 0) {
    int cnt[8] = {0, 0, 0, 0, 0, 0, 0, 0};
    int rank = 0;
    bool ok = true;
    const int myb = (int)blockIdx.x;
    const int myx = (int)(unsigned)xcd_l[myb];
    for (int i = 0; i < 256; ++i) {
      int xc = (int)(unsigned)xcd_l[i];
      if (xc > 7) { ok = false; break; }
      cnt[xc]++;
      if (i < myb && xc == myx) rank++;
    }
    if (ok)
      for (int i = 0; i < 8; ++i) ok &= (cnt[i] == 32);
    map_s[0] = ok ? myx : (myb & 7);
    map_s[1] = ok ? rank : (myb >> 3);
    map_s[2] = ok ? 1 : 0;
  }
  __syncthreads();
  const int bg = map_s[0];
  const int w = map_s[1];
  const bool fast = (map_s[2] != 0);

  const int u0 = w * 16;
  const int tk = tid >> 4;  // 0..31 (K-chunk of 16)
  const int tc = tid & 15;  // col-quad id
  const int gcol = (tc >> 2) * U_ + u0 + (tc & 3) * 4;
  const int wv = tid >> 6;
  const int lane = tid & 63;
  const int bS = tid >> 7;
  const int tS = tid & 127;
  const int rb = tid >> 6;  // reducer role (tid<256)
  const int rc = tid & 63;
  const int rtc = rc >> 2, rcomp = rc & 3;
  const int rg = rtc >> 2;
  const int rui = ((rtc & 3) << 2) | rcomp;
  const int rcol = rg * U_ + u0 + rui;

  __shared__ float attx_l[16 * GB * T_];  // 32 KB
  __shared__ float h_s[GB][U_];           // 8 KB
  __shared__ float4 red2[8][GB][17];
  __shared__ float hUred[8][GB][17];
  __shared__ float sc_s[GB][T_];
  __shared__ float hU_s[GB][16];
  __shared__ float act_s[GB][64];
  __shared__ float c_s[GB][16];
  __shared__ float lsum_s[8];
  __shared__ float Vs_l[16];

  float4 Rw[16];
  float Uw[16];
#pragma unroll
  for (int i = 0; i < 16; ++i)
    Rw[i] = *(const float4*)(Rk + (size_t)(tk * 16 + i) * G_ + gcol);
#pragma unroll
  for (int i = 0; i < 16; ++i)
    Uw[i] = Um[(size_t)(tk * 16 + i) * U_ + u0 + tc];

  for (int idx = tid; idx < 16 * GB * T_; idx += NT) {
    int uc = idx >> 9;
    int b = (idx >> 7) & 3;
    int tt = idx & 127;
    attx_l[idx] = attxT[((size_t)(bg * GB + b) * U_ + u0 + uc) * T_ + tt];
  }
  for (int i = tid; i < GB * U_; i += NT) ((float*)h_s)[i] = 0.f;
  if (tid < GB * 16) ((float*)c_s)[tid] = 0.f;
  if (tid < 16) Vs_l[tid] = V[u0 + tid];
  unsigned* slots = bars + bg * (WPG * SLOTSTRIDE);
  unsigned epoch = 0;
  float* hpg = h_pub + (size_t)bg * GB * U_;
  float* spg = sp_g + (size_t)bg * GB * T_ * WPG;
  float xkv = 0.f;
  if (tid < 256) xkv = bf2f(xk[((size_t)(bg * GB + rb) * T_ + 0) * G_ + rcol]);
  __syncthreads();

  for (int t = 0; t < T_; ++t) {
    // ===== P1a: hU partial (h@Um own u-slice) -> scores -> sp publish
    float hUa[GB];
#pragma unroll
    for (int b = 0; b < GB; ++b) {
      float hu = 0.f;
      const float* hp = &h_s[b][tk * 16];
#pragma unroll
      for (int i = 0; i < 16; ++i) hu += hp[i] * Uw[i];
      hUa[b] = hu;
    }
#pragma unroll
    for (int b = 0; b < GB; ++b) {
      float hu = hUa[b];
      hu += __shfl_down(hu, 32);
      hu += __shfl_down(hu, 16);
      if (lane < 16) hUred[wv][b][lane] = hu;
    }
    __syncthreads();
    if (tid < 64) {
      int b = tid >> 4, u = tid & 15;
      float s = 0.f;
#pragma unroll
      for (int k = 0; k < 8; ++k) s += hUred[k][b][u];
      hU_s[b][u] = s;
    }
    __syncthreads();
    {  // score partials over own 16-u slice, all (b,t'); layout (b,t',w)
      float s = 0.f;
      const float* ax = &attx_l[bS * T_ + tS];
#pragma unroll
      for (int uc = 0; uc < 16; ++uc) {
        float e = tanh_fast(ax[uc * (GB * T_)] + hU_s[bS][uc]);
        s += e * Vs_l[uc];
      }
      pub_f32(fast, &spg[((size_t)bS * T_ + tS) * WPG + w], s);
    }
    grp_arrive(fast, slots, w, ++epoch);  // B1 arrive

    // ===== B1 shadow: the big h@Rk matvec (independent of sp)
    float4 accR[GB];
#pragma unroll
    for (int b = 0; b < GB; ++b) {
      float4 a = make_float4(0.f, 0.f, 0.f, 0.f);
      const float* hp = &h_s[b][tk * 16];
#pragma unroll
      for (int i = 0; i < 16; ++i) {
        float hv = hp[i];
        a.x += hv * Rw[i].x;
        a.y += hv * Rw[i].y;
        a.z += hv * Rw[i].z;
        a.w += hv * Rw[i].w;
      }
      accR[b] = a;
    }
    grp_wait(fast, slots, epoch, &esc_s);  // B1 wait
    inv_l1(fast);                          // L1 clean before fast gathers

    // ===== P2: wide gather -> softmax (no max pass) -> fold -> LSTM
    {
      const float* spp = spg + ((size_t)bS * T_ + tS) * WPG;
      float4 a0, a1, a2, a3, a4, a5, a6, a7;
      gather32(fast, spp, a0, a1, a2, a3, a4, a5, a6, a7);
      float s = (((a0.x + a0.y) + (a0.z + a0.w)) + ((a1.x + a1.y) + (a1.z + a1.w))) +
                (((a2.x + a2.y) + (a2.z + a2.w)) + ((a3.x + a3.y) + (a3.z + a3.w))) +
                (((a4.x + a4.y) + (a4.z + a4.w)) + ((a5.x + a5.y) + (a5.z + a5.w))) +
                (((a6.x + a6.y) + (a6.z + a6.w)) + ((a7.x + a7.y) + (a7.z + a7.w)));
      float e = __expf(s);  // |s| <= ||V||_1 ~ 20: fp32-safe without shift
      sc_s[bS][tS] = e;
      float ls = e;  // lanes of this wave share bS
      for (int o = 32; o > 0; o >>= 1) ls += __shfl_down(ls, o);
      if (lane == 0) lsum_s[wv] = ls;
    }
    __syncthreads();
#pragma unroll
    for (int b = 0; b < GB; ++b) {
      const unsigned short* xap =
          xA + ((size_t)(bg * GB + b) * T_ + tk * 4) * G_ + gcol;
      float4 az = make_float4(0.f, 0.f, 0.f, 0.f);
#pragma unroll
      for (int i = 0; i < 4; ++i) {
        ushort4 xv = *(const ushort4*)(xap + (size_t)i * G_);
        float al = sc_s[b][tk * 4 + i];
        az.x += al * bf2f(xv.x);
        az.y += al * bf2f(xv.y);
        az.z += al * bf2f(xv.z);
        az.w += al * bf2f(xv.w);
      }
      float il = 1.f / (lsum_s[2 * b] + lsum_s[2 * b + 1]);
      float4 comb;
      comb.x = accR[b].x + il * az.x;
      comb.y = accR[b].y + il * az.y;
      comb.z = accR[b].z + il * az.z;
      comb.w = accR[b].w + il * az.w;
      comb.x += __shfl_down(comb.x, 32);
      comb.y += __shfl_down(comb.y, 32);
      comb.z += __shfl_down(comb.z, 32);
      comb.w += __shfl_down(comb.w, 32);
      comb.x += __shfl_down(comb.x, 16);
      comb.y += __shfl_down(comb.y, 16);
      comb.z += __shfl_down(comb.z, 16);
      comb.w += __shfl_down(comb.w, 16);
      if (lane < 16) red2[wv][b][lane] = comb;
    }
    __syncthreads();
    if (tid < 256) {
      float gsum = xkv;
      const float* r2 = (const float*)red2;
#pragma unroll
      for (int k = 0; k < 8; ++k)
        gsum += r2[(((size_t)(k * GB + rb) * 17) + rtc) * 4 + rcomp];
      float gv = (rg == 2) ? tanh_fast(gsum)
                           : fminf(fmaxf(0.2f * gsum + 0.5f, 0.f), 1.f);
      act_s[rb][rg * 16 + rui] = gv;
    }
    __syncthreads();
    if (tid < 64) {  // R7: 1 u per lane (was 4 u per lane on tid<16)
      int b = tid >> 4, ui = tid & 15;
      float i_ = act_s[b][ui];
      float f_ = act_s[b][16 + ui];
      float g_ = act_s[b][32 + ui];
      float o_ = act_s[b][48 + ui];
      float cn = f_ * c_s[b][ui] + i_ * g_;
      c_s[b][ui] = cn;
      float hv = o_ * tanh_fast(cn);
      int gb = bg * GB + b;
      pub_f32(fast, &hpg[(size_t)b * U_ + u0 + ui], hv);
      out[((size_t)gb * T_ + t) * U_ + u0 + ui] = hv;
    }
    grp_arrive(fast, slots, w, ++epoch);  // B2 arrive

    // ===== B2 shadow: prefetch next step's xk
    int tn = (t + 1 < T_) ? t + 1 : t;
    float xkv_n = 0.f;
    if (tid < 256)
      xkv_n = bf2f(xk[((size_t)(bg * GB + rb) * T_ + tn) * G_ + rcol]);
    grp_wait(fast, slots, epoch, &esc_s);  // B2 wait
    inv_l1(fast);                          // L1 clean before h gather

    {
      float4 hv = load4_coh(fast, hpg + tid * 4);
      *(float4*)&((float*)h_s)[tid * 4] = hv;
    }
    xkv = xkv_n;
    __syncthreads();
  }
}

// ---------------------------------------------------------------------------
extern "C" void kernel_launch(void* const* d_in, const int* in_sizes, int n_in,
                              void* d_out, int out_size, void* d_ws,
                              size_t ws_size, hipStream_t stream) {
  (void)in_sizes;
  (void)n_in;
  (void)out_size;
  (void)ws_size;
  const float* x = (const float*)d_in[0];
  const float* Wk = (const float*)d_in[1];
  const float* Rk = (const float*)d_in[2];
  const float* Ak = (const float*)d_in[3];
  const float* Wa = (const float*)d_in[4];
  const float* Ua = (const float*)d_in[5];
  const float* Va = (const float*)d_in[6];
  const float* bias = (const float*)d_in[7];
  const float* ba = (const float*)d_in[8];
  float* out = (float*)d_out;

  char* ws = (char*)d_ws;
  unsigned short* xk_b = (unsigned short*)(ws);            // 16 MiB
  unsigned short* xA_b = (unsigned short*)(ws + 16777216); // 16 MiB
  float* attxT = (float*)(ws + 33554432);                  // 8 MiB
  float* h_pub = (float*)(ws + 41943040);                  // 64 KiB
  float* sp_g = (float*)(ws + 42008576);                   // 512 KiB
  unsigned* bars = (unsigned*)(ws + 42532864);             // 16 KiB

  gemm_bias_t<1><<<dim3(G_ / 64, (B_ * T_) / 64), 256, 0, stream>>>(
      x, Wk, bias, xk_b, G_);
  gemm_bias_t<1><<<dim3(G_ / 64, (B_ * T_) / 64), 256, 0, stream>>>(
      x, Ak, nullptr, xA_b, G_);
  gemm_bias_t<2><<<dim3(U_ / 64, (B_ * T_) / 64), 256, 0, stream>>>(
      x, Wa, ba, attxT, U_);
  (void)hipMemsetAsync(bars, 0, NGRP * WPG * SLOTSTRIDE * sizeof(unsigned),
                       stream);

  attlstm_rec<<<dim3(NGRP * WPG), dim3(NT), 0, stream>>>(
      xk_b, xA_b, attxT, Rk, Ua, Va, h_pub, sp_g, bars, out);
}

// Round 8
// 1604.625 us; speedup vs baseline: 1.4365x; 1.0390x over previous
//
#include <hip/hip_runtime.h>
#include <math.h>

#define B_ 32
#define T_ 128
#define D_ 512
#define U_ 512
#define G_ 2048   // 4U
#define NGRP 8    // batch groups
#define GB 4      // batches per group
#define WPG 32    // workgroups per group
#define NT 512    // threads per WG
#define GK 512    // K dim of precompute GEMMs
#define SLOTSTRIDE 16  // slot padding: 64B apart. word0=epoch, word8=XCD pub

__device__ __forceinline__ unsigned short f2bf(float v) {
  unsigned u = __float_as_uint(v);
  return (unsigned short)((u + 0x7FFFu + ((u >> 16) & 1u)) >> 16);
}
__device__ __forceinline__ float bf2f(unsigned short u) {
  return __uint_as_float(((unsigned)u) << 16);
}

// Device-coherence-point store (baseline path).
__device__ __forceinline__ void dev_store(float* p, float v) {
  __hip_atomic_store(p, v, __ATOMIC_RELAXED, __HIP_MEMORY_SCOPE_AGENT);
}

// Data publish: fast = sc0 (lands in the XCD's L2; same-XCD readers are
// coherent through that L2). slow = baseline agent-scope store.
__device__ __forceinline__ void pub_f32(bool fast, float* p, float v) {
  if (fast)
    asm volatile("global_store_dword %0, %1, off sc0" ::"v"(p), "v"(v)
                 : "memory");
  else
    dev_store(p, v);
}

// sc0 slot load for the fast poll (L2 latency). NO buffer_inv here (R4:
// inv-per-iteration nuked L1 locality + serialized the poll, 1397->2040).
// Barrier ARRIVE stays agent-scope (R7: sc0-arrive + agent mirror on the
// same line ping-pongs L2<->MALL, +40us). R3's asymmetric scheme — agent
// arrive, sc0 poll, 512-try sticky escape — is the verified optimum.
__device__ __forceinline__ unsigned ld_slot_sc0(const unsigned* p) {
  unsigned r;
  asm volatile(
      "global_load_dword %0, %1, off sc0\n\t"
      "s_waitcnt vmcnt(0)"
      : "=&v"(r)
      : "v"(p)
      : "memory");
  return r;
}

// Per-CU vector L1 invalidate before fast-mode data gathers (once per wait).
__device__ __forceinline__ void inv_l1(bool fast) {
  if (fast) asm volatile("buffer_inv sc0" ::: "memory");
}

// 32 contiguous floats as 8 pipelined dwordx4 loads + ONE waitcnt.
__device__ __forceinline__ void gather32(bool fast, const float* p, float4& a0,
                                         float4& a1, float4& a2, float4& a3,
                                         float4& a4, float4& a5, float4& a6,
                                         float4& a7) {
  if (fast) {
    asm volatile(
        "global_load_dwordx4 %0, %8, off sc0\n\t"
        "global_load_dwordx4 %1, %8, off offset:16 sc0\n\t"
        "global_load_dwordx4 %2, %8, off offset:32 sc0\n\t"
        "global_load_dwordx4 %3, %8, off offset:48 sc0\n\t"
        "global_load_dwordx4 %4, %8, off offset:64 sc0\n\t"
        "global_load_dwordx4 %5, %8, off offset:80 sc0\n\t"
        "global_load_dwordx4 %6, %8, off offset:96 sc0\n\t"
        "global_load_dwordx4 %7, %8, off offset:112 sc0\n\t"
        "s_waitcnt vmcnt(0)"
        : "=&v"(a0), "=&v"(a1), "=&v"(a2), "=&v"(a3), "=&v"(a4), "=&v"(a5),
          "=&v"(a6), "=&v"(a7)
        : "v"(p)
        : "memory");
  } else {
    asm volatile(
        "global_load_dwordx4 %0, %8, off sc0 sc1\n\t"
        "global_load_dwordx4 %1, %8, off offset:16 sc0 sc1\n\t"
        "global_load_dwordx4 %2, %8, off offset:32 sc0 sc1\n\t"
        "global_load_dwordx4 %3, %8, off offset:48 sc0 sc1\n\t"
        "global_load_dwordx4 %4, %8, off offset:64 sc0 sc1\n\t"
        "global_load_dwordx4 %5, %8, off offset:80 sc0 sc1\n\t"
        "global_load_dwordx4 %6, %8, off offset:96 sc0 sc1\n\t"
        "global_load_dwordx4 %7, %8, off offset:112 sc0 sc1\n\t"
        "s_waitcnt vmcnt(0)"
        : "=&v"(a0), "=&v"(a1), "=&v"(a2), "=&v"(a3), "=&v"(a4), "=&v"(a5),
          "=&v"(a6), "=&v"(a7)
        : "v"(p)
        : "memory");
  }
}

__device__ __forceinline__ float4 load4_coh(bool fast, const float* p) {
  float4 r;
  if (fast)
    asm volatile(
        "global_load_dwordx4 %0, %1, off sc0\n\t"
        "s_waitcnt vmcnt(0)"
        : "=&v"(r)
        : "v"(p)
        : "memory");
  else
    asm volatile(
        "global_load_dwordx4 %0, %1, off sc0 sc1\n\t"
        "s_waitcnt vmcnt(0)"
        : "=&v"(r)
        : "v"(p)
        : "memory");
  return r;
}

// ---------------------------------------------------------------------------
// Precompute GEMM: C[M,N] = A[M,512] @ W[512,N] + bias  (bias may be null)
// MODE 1: bf16 row-major; MODE 2: fp32 (B,U,T)-transposed
// ---------------------------------------------------------------------------
template <int MODE>
__global__ __launch_bounds__(256) void gemm_bias_t(const float* __restrict__ A,
                                                   const float* __restrict__ W,
                                                   const float* __restrict__ bias,
                                                   void* __restrict__ Cout, int N) {
  __shared__ float As[16][68];
  __shared__ float Ws[16][64];
  const int tid = threadIdx.x;
  const int rowbase = blockIdx.y * 64;
  const int colbase = blockIdx.x * 64;
  const int ty = tid >> 4, tx = tid & 15;
  const int ar = tid >> 2, ak = (tid & 3) << 2;
  const int wk = tid >> 4, wc = (tid & 15) << 2;
  float acc[4][4] = {{0.f, 0.f, 0.f, 0.f}};
  for (int k0 = 0; k0 < GK; k0 += 16) {
    float4 av = *(const float4*)(A + (size_t)(rowbase + ar) * GK + k0 + ak);
    float4 wv = *(const float4*)(W + (size_t)(k0 + wk) * N + colbase + wc);
    __syncthreads();
    As[ak + 0][ar] = av.x;
    As[ak + 1][ar] = av.y;
    As[ak + 2][ar] = av.z;
    As[ak + 3][ar] = av.w;
    *(float4*)(&Ws[wk][wc]) = wv;
    __syncthreads();
#pragma unroll
    for (int kk = 0; kk < 16; ++kk) {
      float4 a = *(const float4*)(&As[kk][ty << 2]);
      float4 wv2 = *(const float4*)(&Ws[kk][tx << 2]);
      float a4[4] = {a.x, a.y, a.z, a.w};
      float w4[4] = {wv2.x, wv2.y, wv2.z, wv2.w};
#pragma unroll
      for (int i = 0; i < 4; ++i)
#pragma unroll
        for (int jj = 0; jj < 4; ++jj) acc[i][jj] += a4[i] * w4[jj];
    }
  }
  float4 bv = bias ? *(const float4*)(bias + colbase + (tx << 2))
                   : make_float4(0.f, 0.f, 0.f, 0.f);
#pragma unroll
  for (int i = 0; i < 4; ++i) {
    const int row = rowbase + (ty << 2) + i;
    float o[4] = {acc[i][0] + bv.x, acc[i][1] + bv.y, acc[i][2] + bv.z,
                  acc[i][3] + bv.w};
    if (MODE == 1) {
      ushort4 ob;
      ob.x = f2bf(o[0]); ob.y = f2bf(o[1]); ob.z = f2bf(o[2]); ob.w = f2bf(o[3]);
      *(ushort4*)((unsigned short*)Cout + (size_t)row * N + colbase + (tx << 2)) = ob;
    } else {
      const int b = row >> 7, tt = row & 127;
#pragma unroll
      for (int jj = 0; jj < 4; ++jj) {
        int u = colbase + (tx << 2) + jj;
        ((float*)Cout)[((size_t)b * U_ + u) * T_ + tt] = o[jj];
      }
    }
  }
}

__device__ __forceinline__ float tanh_fast(float x) {
  return 1.f - 2.f / (__expf(2.f * x) + 1.f);
}

// Split-phase RMW-free barrier (R3-verified structure, 1397 us). Arrive:
// explicit vmcnt(0) (inline-asm data stores are invisible to the compiler's
// barrier lowering) + syncthreads + own padded slot store (agent scope).
// Wait: parallel 32-slot poll; fast mode polls with sc0 (L2) and
// sticky-escapes to the agent-scope poll after 512 tries ->
// deadlock-impossible in any coherence interpretation. Independent work
// goes between arrive and wait.
__device__ __forceinline__ void grp_arrive(unsigned* slots, int w,
                                           unsigned epoch) {
  asm volatile("s_waitcnt vmcnt(0)" ::: "memory");
  __syncthreads();
  if (threadIdx.x == 0)
    __hip_atomic_store(&slots[w * SLOTSTRIDE], epoch, __ATOMIC_RELAXED,
                       __HIP_MEMORY_SCOPE_AGENT);
}
__device__ __forceinline__ void grp_wait(bool fast, const unsigned* slots,
                                         unsigned epoch, int* esc_flag) {
  if (threadIdx.x < 64) {
    bool esc = !fast || (*esc_flag != 0);
    int tries = 0;
    bool done = false;
    do {
      unsigned v;
      if (threadIdx.x < WPG) {
        v = esc ? __hip_atomic_load(&slots[threadIdx.x * SLOTSTRIDE],
                                    __ATOMIC_RELAXED, __HIP_MEMORY_SCOPE_AGENT)
                : ld_slot_sc0(&slots[threadIdx.x * SLOTSTRIDE]);
      } else {
        v = epoch;
      }
      done = __all(v >= epoch);
      if (!done && !esc && ++tries > 512) {
        esc = true;
        if (threadIdx.x == 0) *esc_flag = 1;
      }
    } while (!done);
  }
  __syncthreads();
}

// ---------------------------------------------------------------------------
// Weight-stationary recurrence, split-phase barriers. 8 groups x 32 WGs x
// 512 threads. B1 wait hidden under the h@Rk matvec; B2 wait hides the xk
// prefetch. sp layout (b,t,w): reader's 32 partials = one 128B block.
// Phase 0: each WG publishes HW_REG_XCC_ID into word 8 of its own barrier
// slot; if every XCD holds exactly 32 WGs, groups remap to bg=xcd /
// w=rank-in-xcd so all group-internal bulk traffic (sp, h) stays in that
// XCD's shared L2 (sc0) instead of the device coherence point. Fallback ->
// baseline path. R3 verified: fast path engages (WRITE_SIZE 567->86 MB).
// R8 = exact R3 + ONLY the LSTM-tail widen (tid<16 -> tid<64, 1 u/lane,
// correctness verified in R7 with bit-identical absmax). Refuted levers,
// do not retry: xAv reg-hoist (compiler remats, R5/R6), sc0-arrive w/
// mirror (line ping-pong, R7), inv-in-poll (R4).
// ---------------------------------------------------------------------------
__global__ __launch_bounds__(NT) void attlstm_rec(
    const unsigned short* __restrict__ xk,  // (B,T,4U) bf16
    const unsigned short* __restrict__ xA,  // (B,T,4U) bf16
    const float* __restrict__ attxT,        // (B,U,T) fp32
    const float* __restrict__ Rk,           // (U,4U)
    const float* __restrict__ Um,           // (U,U)
    const float* __restrict__ V,            // (U)
    float* __restrict__ h_pub,              // (NGRP,GB,U)
    float* __restrict__ sp_g,               // (NGRP,GB,T,WPG)
    unsigned* __restrict__ bars,            // (NGRP,WPG*SLOTSTRIDE)
    float* __restrict__ out) {              // (B,T,U)
  const int tid = threadIdx.x;

  // ===== Phase 0 (one-time): XCD placement discovery & group remap =====
  __shared__ unsigned char xcd_l[256];
  __shared__ int map_s[3];
  __shared__ int esc_s;
  unsigned myxcd;
  asm volatile("s_getreg_b32 %0, hwreg(HW_REG_XCC_ID)" : "=s"(myxcd));
  if (tid == 0)
    __hip_atomic_store(&bars[(unsigned)blockIdx.x * SLOTSTRIDE + 8],
                       (myxcd & 0xffu) + 1u, __ATOMIC_RELAXED,
                       __HIP_MEMORY_SCOPE_AGENT);
  if (tid < 256) {
    unsigned v;
    do {  // same co-residency requirement as the baseline's own barriers
      v = __hip_atomic_load(&bars[(unsigned)tid * SLOTSTRIDE + 8],
                            __ATOMIC_RELAXED, __HIP_MEMORY_SCOPE_AGENT);
    } while (v == 0u);
    xcd_l[tid] = (unsigned char)(v - 1u);
  }
  if (tid == 0) esc_s = 0;
  __syncthreads();
  if (tid == 0) {
    int cnt[8] = {0, 0, 0, 0, 0, 0, 0, 0};
    int rank = 0;
    bool ok = true;
    const int myb = (int)blockIdx.x;
    const int myx = (int)(unsigned)xcd_l[myb];
    for (int i = 0; i < 256; ++i) {
      int xc = (int)(unsigned)xcd_l[i];
      if (xc > 7) { ok = false; break; }
      cnt[xc]++;
      if (i < myb && xc == myx) rank++;
    }
    if (ok)
      for (int i = 0; i < 8; ++i) ok &= (cnt[i] == 32);
    map_s[0] = ok ? myx : (myb & 7);
    map_s[1] = ok ? rank : (myb >> 3);
    map_s[2] = ok ? 1 : 0;
  }
  __syncthreads();
  const int bg = map_s[0];
  const int w = map_s[1];
  const bool fast = (map_s[2] != 0);

  const int u0 = w * 16;
  const int tk = tid >> 4;  // 0..31 (K-chunk of 16)
  const int tc = tid & 15;  // col-quad id
  const int gcol = (tc >> 2) * U_ + u0 + (tc & 3) * 4;
  const int wv = tid >> 6;
  const int lane = tid & 63;
  const int bS = tid >> 7;
  const int tS = tid & 127;
  const int rb = tid >> 6;  // reducer role (tid<256)
  const int rc = tid & 63;
  const int rtc = rc >> 2, rcomp = rc & 3;
  const int rg = rtc >> 2;
  const int rui = ((rtc & 3) << 2) | rcomp;
  const int rcol = rg * U_ + u0 + rui;

  __shared__ float attx_l[16 * GB * T_];  // 32 KB
  __shared__ float h_s[GB][U_];           // 8 KB
  __shared__ float4 red2[8][GB][17];
  __shared__ float hUred[8][GB][17];
  __shared__ float sc_s[GB][T_];
  __shared__ float hU_s[GB][16];
  __shared__ float act_s[GB][64];
  __shared__ float c_s[GB][16];
  __shared__ float lsum_s[8];
  __shared__ float Vs_l[16];

  float4 Rw[16];
  float Uw[16];
#pragma unroll
  for (int i = 0; i < 16; ++i)
    Rw[i] = *(const float4*)(Rk + (size_t)(tk * 16 + i) * G_ + gcol);
#pragma unroll
  for (int i = 0; i < 16; ++i)
    Uw[i] = Um[(size_t)(tk * 16 + i) * U_ + u0 + tc];

  for (int idx = tid; idx < 16 * GB * T_; idx += NT) {
    int uc = idx >> 9;
    int b = (idx >> 7) & 3;
    int tt = idx & 127;
    attx_l[idx] = attxT[((size_t)(bg * GB + b) * U_ + u0 + uc) * T_ + tt];
  }
  for (int i = tid; i < GB * U_; i += NT) ((float*)h_s)[i] = 0.f;
  if (tid < GB * 16) ((float*)c_s)[tid] = 0.f;
  if (tid < 16) Vs_l[tid] = V[u0 + tid];
  unsigned* slots = bars + bg * (WPG * SLOTSTRIDE);
  unsigned epoch = 0;
  float* hpg = h_pub + (size_t)bg * GB * U_;
  float* spg = sp_g + (size_t)bg * GB * T_ * WPG;
  float xkv = 0.f;
  if (tid < 256) xkv = bf2f(xk[((size_t)(bg * GB + rb) * T_ + 0) * G_ + rcol]);
  __syncthreads();

  for (int t = 0; t < T_; ++t) {
    // ===== P1a: hU partial (h@Um own u-slice) -> scores -> sp publish
    float hUa[GB];
#pragma unroll
    for (int b = 0; b < GB; ++b) {
      float hu = 0.f;
      const float* hp = &h_s[b][tk * 16];
#pragma unroll
      for (int i = 0; i < 16; ++i) hu += hp[i] * Uw[i];
      hUa[b] = hu;
    }
#pragma unroll
    for (int b = 0; b < GB; ++b) {
      float hu = hUa[b];
      hu += __shfl_down(hu, 32);
      hu += __shfl_down(hu, 16);
      if (lane < 16) hUred[wv][b][lane] = hu;
    }
    __syncthreads();
    if (tid < 64) {
      int b = tid >> 4, u = tid & 15;
      float s = 0.f;
#pragma unroll
      for (int k = 0; k < 8; ++k) s += hUred[k][b][u];
      hU_s[b][u] = s;
    }
    __syncthreads();
    {  // score partials over own 16-u slice, all (b,t'); layout (b,t',w)
      float s = 0.f;
      const float* ax = &attx_l[bS * T_ + tS];
#pragma unroll
      for (int uc = 0; uc < 16; ++uc) {
        float e = tanh_fast(ax[uc * (GB * T_)] + hU_s[bS][uc]);
        s += e * Vs_l[uc];
      }
      pub_f32(fast, &spg[((size_t)bS * T_ + tS) * WPG + w], s);
    }
    grp_arrive(slots, w, ++epoch);  // B1 arrive

    // ===== B1 shadow: the big h@Rk matvec (independent of sp)
    float4 accR[GB];
#pragma unroll
    for (int b = 0; b < GB; ++b) {
      float4 a = make_float4(0.f, 0.f, 0.f, 0.f);
      const float* hp = &h_s[b][tk * 16];
#pragma unroll
      for (int i = 0; i < 16; ++i) {
        float hv = hp[i];
        a.x += hv * Rw[i].x;
        a.y += hv * Rw[i].y;
        a.z += hv * Rw[i].z;
        a.w += hv * Rw[i].w;
      }
      accR[b] = a;
    }
    grp_wait(fast, slots, epoch, &esc_s);  // B1 wait
    inv_l1(fast);                          // L1 clean before fast gathers

    // ===== P2: wide gather -> softmax (no max pass) -> fold -> LSTM
    {
      const float* spp = spg + ((size_t)bS * T_ + tS) * WPG;
      float4 a0, a1, a2, a3, a4, a5, a6, a7;
      gather32(fast, spp, a0, a1, a2, a3, a4, a5, a6, a7);
      float s = (((a0.x + a0.y) + (a0.z + a0.w)) + ((a1.x + a1.y) + (a1.z + a1.w))) +
                (((a2.x + a2.y) + (a2.z + a2.w)) + ((a3.x + a3.y) + (a3.z + a3.w))) +
                (((a4.x + a4.y) + (a4.z + a4.w)) + ((a5.x + a5.y) + (a5.z + a5.w))) +
                (((a6.x + a6.y) + (a6.z + a6.w)) + ((a7.x + a7.y) + (a7.z + a7.w)));
      float e = __expf(s);  // |s| <= ||V||_1 ~ 20: fp32-safe without shift
      sc_s[bS][tS] = e;
      float ls = e;  // lanes of this wave share bS
      for (int o = 32; o > 0; o >>= 1) ls += __shfl_down(ls, o);
      if (lane == 0) lsum_s[wv] = ls;
    }
    __syncthreads();
#pragma unroll
    for (int b = 0; b < GB; ++b) {
      const unsigned short* xap =
          xA + ((size_t)(bg * GB + b) * T_ + tk * 4) * G_ + gcol;
      float4 az = make_float4(0.f, 0.f, 0.f, 0.f);
#pragma unroll
      for (int i = 0; i < 4; ++i) {
        ushort4 xv = *(const ushort4*)(xap + (size_t)i * G_);
        float al = sc_s[b][tk * 4 + i];
        az.x += al * bf2f(xv.x);
        az.y += al * bf2f(xv.y);
        az.z += al * bf2f(xv.z);
        az.w += al * bf2f(xv.w);
      }
      float il = 1.f / (lsum_s[2 * b] + lsum_s[2 * b + 1]);
      float4 comb;
      comb.x = accR[b].x + il * az.x;
      comb.y = accR[b].y + il * az.y;
      comb.z = accR[b].z + il * az.z;
      comb.w = accR[b].w + il * az.w;
      comb.x += __shfl_down(comb.x, 32);
      comb.y += __shfl_down(comb.y, 32);
      comb.z += __shfl_down(comb.z, 32);
      comb.w += __shfl_down(comb.w, 32);
      comb.x += __shfl_down(comb.x, 16);
      comb.y += __shfl_down(comb.y, 16);
      comb.z += __shfl_down(comb.z, 16);
      comb.w += __shfl_down(comb.w, 16);
      if (lane < 16) red2[wv][b][lane] = comb;
    }
    __syncthreads();
    if (tid < 256) {
      float gsum = xkv;
      const float* r2 = (const float*)red2;
#pragma unroll
      for (int k = 0; k < 8; ++k)
        gsum += r2[(((size_t)(k * GB + rb) * 17) + rtc) * 4 + rcomp];
      float gv = (rg == 2) ? tanh_fast(gsum)
                           : fminf(fmaxf(0.2f * gsum + 0.5f, 0.f), 1.f);
      act_s[rb][rg * 16 + rui] = gv;
    }
    __syncthreads();
    if (tid < 64) {  // widened LSTM tail: 1 u per lane (R7-verified math)
      int b = tid >> 4, ui = tid & 15;
      float i_ = act_s[b][ui];
      float f_ = act_s[b][16 + ui];
      float g_ = act_s[b][32 + ui];
      float o_ = act_s[b][48 + ui];
      float cn = f_ * c_s[b][ui] + i_ * g_;
      c_s[b][ui] = cn;
      float hv = o_ * tanh_fast(cn);
      int gb = bg * GB + b;
      pub_f32(fast, &hpg[(size_t)b * U_ + u0 + ui], hv);
      out[((size_t)gb * T_ + t) * U_ + u0 + ui] = hv;
    }
    grp_arrive(slots, w, ++epoch);  // B2 arrive

    // ===== B2 shadow: prefetch next step's xk
    int tn = (t + 1 < T_) ? t + 1 : t;
    float xkv_n = 0.f;
    if (tid < 256)
      xkv_n = bf2f(xk[((size_t)(bg * GB + rb) * T_ + tn) * G_ + rcol]);
    grp_wait(fast, slots, epoch, &esc_s);  // B2 wait
    inv_l1(fast);                          // L1 clean before h gather

    {
      float4 hv = load4_coh(fast, hpg + tid * 4);
      *(float4*)&((float*)h_s)[tid * 4] = hv;
    }
    xkv = xkv_n;
    __syncthreads();
  }
}

// ---------------------------------------------------------------------------
extern "C" void kernel_launch(void* const* d_in, const int* in_sizes, int n_in,
                              void* d_out, int out_size, void* d_ws,
                              size_t ws_size, hipStream_t stream) {
  (void)in_sizes;
  (void)n_in;
  (void)out_size;
  (void)ws_size;
  const float* x = (const float*)d_in[0];
  const float* Wk = (const float*)d_in[1];
  const float* Rk = (const float*)d_in[2];
  const float* Ak = (const float*)d_in[3];
  const float* Wa = (const float*)d_in[4];
  const float* Ua = (const float*)d_in[5];
  const float* Va = (const float*)d_in[6];
  const float* bias = (const float*)d_in[7];
  const float* ba = (const float*)d_in[8];
  float* out = (float*)d_out;

  char* ws = (char*)d_ws;
  unsigned short* xk_b = (unsigned short*)(ws);            // 16 MiB
  unsigned short* xA_b = (unsigned short*)(ws + 16777216); // 16 MiB
  float* attxT = (float*)(ws + 33554432);                  // 8 MiB
  float* h_pub = (float*)(ws + 41943040);                  // 64 KiB
  float* sp_g = (float*)(ws + 42008576);                   // 512 KiB
  unsigned* bars = (unsigned*)(ws + 42532864);             // 16 KiB

  gemm_bias_t<1><<<dim3(G_ / 64, (B_ * T_) / 64), 256, 0, stream>>>(
      x, Wk, bias, xk_b, G_);
  gemm_bias_t<1><<<dim3(G_ / 64, (B_ * T_) / 64), 256, 0, stream>>>(
      x, Ak, nullptr, xA_b, G_);
  gemm_bias_t<2><<<dim3(U_ / 64, (B_ * T_) / 64), 256, 0, stream>>>(
      x, Wa, ba, attxT, U_);
  (void)hipMemsetAsync(bars, 0, NGRP * WPG * SLOTSTRIDE * sizeof(unsigned),
                       stream);

  attlstm_rec<<<dim3(NGRP * WPG), dim3(NT), 0, stream>>>(
      xk_b, xA_b, attxT, Rk, Ua, Va, h_pub, sp_g, bars, out);
}

// Round 9
// 1513.034 us; speedup vs baseline: 1.5235x; 1.0605x over previous
//
#include <hip/hip_runtime.h>
#include <math.h>

#define B_ 32
#define T_ 128
#define D_ 512
#define U_ 512
#define G_ 2048   // 4U
#define NGRP 8    // batch groups
#define GB 4      // batches per group
#define WPG 32    // workgroups per group
#define NT 512    // threads per WG
#define GK 512    // K dim of precompute GEMMs
#define SLOTSTRIDE 16  // slot padding: 64B apart. word0=epoch, word8=XCD pub

__device__ __forceinline__ unsigned short f2bf(float v) {
  unsigned u = __float_as_uint(v);
  return (unsigned short)((u + 0x7FFFu + ((u >> 16) & 1u)) >> 16);
}
__device__ __forceinline__ float bf2f(unsigned short u) {
  return __uint_as_float(((unsigned)u) << 16);
}

// Device-coherence-point store (baseline path).
__device__ __forceinline__ void dev_store(float* p, float v) {
  __hip_atomic_store(p, v, __ATOMIC_RELAXED, __HIP_MEMORY_SCOPE_AGENT);
}

// Data publish: fast = sc0 (lands in the XCD's L2; same-XCD readers are
// coherent through that L2). slow = baseline agent-scope store.
__device__ __forceinline__ void pub_f32(bool fast, float* p, float v) {
  if (fast)
    asm volatile("global_store_dword %0, %1, off sc0" ::"v"(p), "v"(v)
                 : "memory");
  else
    dev_store(p, v);
}

// sc0 slot load for the fast poll (L2 latency). NO buffer_inv here (R4:
// inv-per-iteration nuked L1 locality + serialized the poll, 1397->2040).
// Barrier ARRIVE stays agent-scope (R7: sc0-arrive + agent mirror on the
// same line ping-pongs L2<->MALL, +40us). R3's asymmetric scheme — agent
// arrive, sc0 poll, 512-try sticky escape — is the verified optimum.
__device__ __forceinline__ unsigned ld_slot_sc0(const unsigned* p) {
  unsigned r;
  asm volatile(
      "global_load_dword %0, %1, off sc0\n\t"
      "s_waitcnt vmcnt(0)"
      : "=&v"(r)
      : "v"(p)
      : "memory");
  return r;
}

// Per-CU vector L1 invalidate before fast-mode data gathers (once per wait).
__device__ __forceinline__ void inv_l1(bool fast) {
  if (fast) asm volatile("buffer_inv sc0" ::: "memory");
}

// 32 contiguous floats as 8 pipelined dwordx4 loads + ONE waitcnt.
__device__ __forceinline__ void gather32(bool fast, const float* p, float4& a0,
                                         float4& a1, float4& a2, float4& a3,
                                         float4& a4, float4& a5, float4& a6,
                                         float4& a7) {
  if (fast) {
    asm volatile(
        "global_load_dwordx4 %0, %8, off sc0\n\t"
        "global_load_dwordx4 %1, %8, off offset:16 sc0\n\t"
        "global_load_dwordx4 %2, %8, off offset:32 sc0\n\t"
        "global_load_dwordx4 %3, %8, off offset:48 sc0\n\t"
        "global_load_dwordx4 %4, %8, off offset:64 sc0\n\t"
        "global_load_dwordx4 %5, %8, off offset:80 sc0\n\t"
        "global_load_dwordx4 %6, %8, off offset:96 sc0\n\t"
        "global_load_dwordx4 %7, %8, off offset:112 sc0\n\t"
        "s_waitcnt vmcnt(0)"
        : "=&v"(a0), "=&v"(a1), "=&v"(a2), "=&v"(a3), "=&v"(a4), "=&v"(a5),
          "=&v"(a6), "=&v"(a7)
        : "v"(p)
        : "memory");
  } else {
    asm volatile(
        "global_load_dwordx4 %0, %8, off sc0 sc1\n\t"
        "global_load_dwordx4 %1, %8, off offset:16 sc0 sc1\n\t"
        "global_load_dwordx4 %2, %8, off offset:32 sc0 sc1\n\t"
        "global_load_dwordx4 %3, %8, off offset:48 sc0 sc1\n\t"
        "global_load_dwordx4 %4, %8, off offset:64 sc0 sc1\n\t"
        "global_load_dwordx4 %5, %8, off offset:80 sc0 sc1\n\t"
        "global_load_dwordx4 %6, %8, off offset:96 sc0 sc1\n\t"
        "global_load_dwordx4 %7, %8, off offset:112 sc0 sc1\n\t"
        "s_waitcnt vmcnt(0)"
        : "=&v"(a0), "=&v"(a1), "=&v"(a2), "=&v"(a3), "=&v"(a4), "=&v"(a5),
          "=&v"(a6), "=&v"(a7)
        : "v"(p)
        : "memory");
  }
}

__device__ __forceinline__ float4 load4_coh(bool fast, const float* p) {
  float4 r;
  if (fast)
    asm volatile(
        "global_load_dwordx4 %0, %1, off sc0\n\t"
        "s_waitcnt vmcnt(0)"
        : "=&v"(r)
        : "v"(p)
        : "memory");
  else
    asm volatile(
        "global_load_dwordx4 %0, %1, off sc0 sc1\n\t"
        "s_waitcnt vmcnt(0)"
        : "=&v"(r)
        : "v"(p)
        : "memory");
  return r;
}

// ---------------------------------------------------------------------------
// Precompute GEMM: C[M,N] = A[M,512] @ W[512,N] + bias  (bias may be null)
// MODE 1: bf16 row-major; MODE 2: fp32 (B,U,T)-transposed
// ---------------------------------------------------------------------------
template <int MODE>
__global__ __launch_bounds__(256) void gemm_bias_t(const float* __restrict__ A,
                                                   const float* __restrict__ W,
                                                   const float* __restrict__ bias,
                                                   void* __restrict__ Cout, int N) {
  __shared__ float As[16][68];
  __shared__ float Ws[16][64];
  const int tid = threadIdx.x;
  const int rowbase = blockIdx.y * 64;
  const int colbase = blockIdx.x * 64;
  const int ty = tid >> 4, tx = tid & 15;
  const int ar = tid >> 2, ak = (tid & 3) << 2;
  const int wk = tid >> 4, wc = (tid & 15) << 2;
  float acc[4][4] = {{0.f, 0.f, 0.f, 0.f}};
  for (int k0 = 0; k0 < GK; k0 += 16) {
    float4 av = *(const float4*)(A + (size_t)(rowbase + ar) * GK + k0 + ak);
    float4 wv = *(const float4*)(W + (size_t)(k0 + wk) * N + colbase + wc);
    __syncthreads();
    As[ak + 0][ar] = av.x;
    As[ak + 1][ar] = av.y;
    As[ak + 2][ar] = av.z;
    As[ak + 3][ar] = av.w;
    *(float4*)(&Ws[wk][wc]) = wv;
    __syncthreads();
#pragma unroll
    for (int kk = 0; kk < 16; ++kk) {
      float4 a = *(const float4*)(&As[kk][ty << 2]);
      float4 wv2 = *(const float4*)(&Ws[kk][tx << 2]);
      float a4[4] = {a.x, a.y, a.z, a.w};
      float w4[4] = {wv2.x, wv2.y, wv2.z, wv2.w};
#pragma unroll
      for (int i = 0; i < 4; ++i)
#pragma unroll
        for (int jj = 0; jj < 4; ++jj) acc[i][jj] += a4[i] * w4[jj];
    }
  }
  float4 bv = bias ? *(const float4*)(bias + colbase + (tx << 2))
                   : make_float4(0.f, 0.f, 0.f, 0.f);
#pragma unroll
  for (int i = 0; i < 4; ++i) {
    const int row = rowbase + (ty << 2) + i;
    float o[4] = {acc[i][0] + bv.x, acc[i][1] + bv.y, acc[i][2] + bv.z,
                  acc[i][3] + bv.w};
    if (MODE == 1) {
      ushort4 ob;
      ob.x = f2bf(o[0]); ob.y = f2bf(o[1]); ob.z = f2bf(o[2]); ob.w = f2bf(o[3]);
      *(ushort4*)((unsigned short*)Cout + (size_t)row * N + colbase + (tx << 2)) = ob;
    } else {
      const int b = row >> 7, tt = row & 127;
#pragma unroll
      for (int jj = 0; jj < 4; ++jj) {
        int u = colbase + (tx << 2) + jj;
        ((float*)Cout)[((size_t)b * U_ + u) * T_ + tt] = o[jj];
      }
    }
  }
}

__device__ __forceinline__ float tanh_fast(float x) {
  return 1.f - 2.f / (__expf(2.f * x) + 1.f);
}

// Split-phase RMW-free barrier (R3-verified structure). Arrive: explicit
// vmcnt(0) (inline-asm data stores are invisible to the compiler's barrier
// lowering) + syncthreads + own padded slot store (agent scope). Wait:
// parallel 32-slot poll; fast mode polls with sc0 (L2) and sticky-escapes
// to the agent-scope poll after 512 tries -> deadlock-impossible in any
// coherence interpretation. Independent work goes between arrive and wait.
__device__ __forceinline__ void grp_arrive(unsigned* slots, int w,
                                           unsigned epoch) {
  asm volatile("s_waitcnt vmcnt(0)" ::: "memory");
  __syncthreads();
  if (threadIdx.x == 0)
    __hip_atomic_store(&slots[w * SLOTSTRIDE], epoch, __ATOMIC_RELAXED,
                       __HIP_MEMORY_SCOPE_AGENT);
}
__device__ __forceinline__ void grp_wait(bool fast, const unsigned* slots,
                                         unsigned epoch, int* esc_flag) {
  if (threadIdx.x < 64) {
    bool esc = !fast || (*esc_flag != 0);
    int tries = 0;
    bool done = false;
    do {
      unsigned v;
      if (threadIdx.x < WPG) {
        v = esc ? __hip_atomic_load(&slots[threadIdx.x * SLOTSTRIDE],
                                    __ATOMIC_RELAXED, __HIP_MEMORY_SCOPE_AGENT)
                : ld_slot_sc0(&slots[threadIdx.x * SLOTSTRIDE]);
      } else {
        v = epoch;
      }
      done = __all(v >= epoch);
      if (!done && !esc && ++tries > 512) {
        esc = true;
        if (threadIdx.x == 0) *esc_flag = 1;
      }
    } while (!done);
  }
  __syncthreads();
}

// ---------------------------------------------------------------------------
// Weight-stationary recurrence, split-phase barriers. 8 groups x 32 WGs x
// 512 threads. B1 wait hidden under the h@Rk matvec; B2 wait hides the xk
// prefetch. sp layout (b,t,w): reader's 32 partials = one 128B block.
// Phase 0: XCD placement discovery -> bg=xcd / w=rank-in-xcd remap so all
// group-internal traffic stays in the XCD's shared L2 (sc0); fallback ->
// placement-independent agent-scope path (G16-safe).
// R9 NEW: the WG's time-invariant xA fold slice (4b x 128t' x 64col bf16 =
// 64 KB) is staged ONCE into LDS (gfx950: 160 KB/CU addressable; 1 WG/CU).
// Removes 64 KB/CU/step of critical-path L2 reads. Reg-hoist of the same
// data was refuted (R5/R6: compiler remats); LDS cannot be remat'd away.
// Refuted levers, do not retry: sc0-arrive w/ mirror (R7), inv-in-poll (R4).
// ---------------------------------------------------------------------------
__global__ __launch_bounds__(NT) void attlstm_rec(
    const unsigned short* __restrict__ xk,  // (B,T,4U) bf16
    const unsigned short* __restrict__ xA,  // (B,T,4U) bf16
    const float* __restrict__ attxT,        // (B,U,T) fp32
    const float* __restrict__ Rk,           // (U,4U)
    const float* __restrict__ Um,           // (U,U)
    const float* __restrict__ V,            // (U)
    float* __restrict__ h_pub,              // (NGRP,GB,U)
    float* __restrict__ sp_g,               // (NGRP,GB,T,WPG)
    unsigned* __restrict__ bars,            // (NGRP,WPG*SLOTSTRIDE)
    float* __restrict__ out) {              // (B,T,U)
  const int tid = threadIdx.x;

  // ===== Phase 0 (one-time): XCD placement discovery & group remap =====
  __shared__ unsigned char xcd_l[256];
  __shared__ int map_s[3];
  __shared__ int esc_s;
  unsigned myxcd;
  asm volatile("s_getreg_b32 %0, hwreg(HW_REG_XCC_ID)" : "=s"(myxcd));
  if (tid == 0)
    __hip_atomic_store(&bars[(unsigned)blockIdx.x * SLOTSTRIDE + 8],
                       (myxcd & 0xffu) + 1u, __ATOMIC_RELAXED,
                       __HIP_MEMORY_SCOPE_AGENT);
  if (tid < 256) {
    unsigned v;
    do {  // same co-residency requirement as the baseline's own barriers
      v = __hip_atomic_load(&bars[(unsigned)tid * SLOTSTRIDE + 8],
                            __ATOMIC_RELAXED, __HIP_MEMORY_SCOPE_AGENT);
    } while (v == 0u);
    xcd_l[tid] = (unsigned char)(v - 1u);
  }
  if (tid == 0) esc_s = 0;
  __syncthreads();
  if (tid == 0) {
    int cnt[8] = {0, 0, 0, 0, 0, 0, 0, 0};
    int rank = 0;
    bool ok = true;
    const int myb = (int)blockIdx.x;
    const int myx = (int)(unsigned)xcd_l[myb];
    for (int i = 0; i < 256; ++i) {
      int xc = (int)(unsigned)xcd_l[i];
      if (xc > 7) { ok = false; break; }
      cnt[xc]++;
      if (i < myb && xc == myx) rank++;
    }
    if (ok)
      for (int i = 0; i < 8; ++i) ok &= (cnt[i] == 32);
    map_s[0] = ok ? myx : (myb & 7);
    map_s[1] = ok ? rank : (myb >> 3);
    map_s[2] = ok ? 1 : 0;
  }
  __syncthreads();
  const int bg = map_s[0];
  const int w = map_s[1];
  const bool fast = (map_s[2] != 0);

  const int u0 = w * 16;
  const int tk = tid >> 4;  // 0..31 (K-chunk of 16)
  const int tc = tid & 15;  // col-quad id
  const int gcol = (tc >> 2) * U_ + u0 + (tc & 3) * 4;
  const int wv = tid >> 6;
  const int lane = tid & 63;
  const int bS = tid >> 7;
  const int tS = tid & 127;
  const int rb = tid >> 6;  // reducer role (tid<256)
  const int rc = tid & 63;
  const int rtc = rc >> 2, rcomp = rc & 3;
  const int rg = rtc >> 2;
  const int rui = ((rtc & 3) << 2) | rcomp;
  const int rcol = rg * U_ + u0 + rui;

  __shared__ float attx_l[16 * GB * T_];   // 32 KB
  __shared__ ushort4 xA_l[GB][T_][16];     // 64 KB: fold slice (b,t',gate*4+q)
  __shared__ float h_s[GB][U_];            // 8 KB
  __shared__ float4 red2[8][GB][17];
  __shared__ float hUred[8][GB][17];
  __shared__ float sc_s[GB][T_];
  __shared__ float hU_s[GB][16];
  __shared__ float act_s[GB][64];
  __shared__ float c_s[GB][16];
  __shared__ float lsum_s[8];
  __shared__ float Vs_l[16];

  float4 Rw[16];
  float Uw[16];
#pragma unroll
  for (int i = 0; i < 16; ++i)
    Rw[i] = *(const float4*)(Rk + (size_t)(tk * 16 + i) * G_ + gcol);
#pragma unroll
  for (int i = 0; i < 16; ++i)
    Uw[i] = Um[(size_t)(tk * 16 + i) * U_ + u0 + tc];

  for (int idx = tid; idx < 16 * GB * T_; idx += NT) {
    int uc = idx >> 9;
    int b = (idx >> 7) & 3;
    int tt = idx & 127;
    attx_l[idx] = attxT[((size_t)(bg * GB + b) * U_ + u0 + uc) * T_ + tt];
  }
  // One-time xA slice stage: (b, t', gate g, quad q) -> xA_l[b][t'][g*4+q]
  for (int idx = tid; idx < GB * T_ * 16; idx += NT) {
    int gq = idx & 15;
    int tt = (idx >> 4) & 127;
    int b = idx >> 11;
    int g = gq >> 2, q = gq & 3;
    ((ushort4*)xA_l)[idx] = *(const ushort4*)(
        xA + ((size_t)(bg * GB + b) * T_ + tt) * G_ + g * U_ + u0 + q * 4);
  }
  for (int i = tid; i < GB * U_; i += NT) ((float*)h_s)[i] = 0.f;
  if (tid < GB * 16) ((float*)c_s)[tid] = 0.f;
  if (tid < 16) Vs_l[tid] = V[u0 + tid];
  unsigned* slots = bars + bg * (WPG * SLOTSTRIDE);
  unsigned epoch = 0;
  float* hpg = h_pub + (size_t)bg * GB * U_;
  float* spg = sp_g + (size_t)bg * GB * T_ * WPG;
  float xkv = 0.f;
  if (tid < 256) xkv = bf2f(xk[((size_t)(bg * GB + rb) * T_ + 0) * G_ + rcol]);
  __syncthreads();

  for (int t = 0; t < T_; ++t) {
    // ===== P1a: hU partial (h@Um own u-slice) -> scores -> sp publish
    float hUa[GB];
#pragma unroll
    for (int b = 0; b < GB; ++b) {
      float hu = 0.f;
      const float* hp = &h_s[b][tk * 16];
#pragma unroll
      for (int i = 0; i < 16; ++i) hu += hp[i] * Uw[i];
      hUa[b] = hu;
    }
#pragma unroll
    for (int b = 0; b < GB; ++b) {
      float hu = hUa[b];
      hu += __shfl_down(hu, 32);
      hu += __shfl_down(hu, 16);
      if (lane < 16) hUred[wv][b][lane] = hu;
    }
    __syncthreads();
    if (tid < 64) {
      int b = tid >> 4, u = tid & 15;
      float s = 0.f;
#pragma unroll
      for (int k = 0; k < 8; ++k) s += hUred[k][b][u];
      hU_s[b][u] = s;
    }
    __syncthreads();
    {  // score partials over own 16-u slice, all (b,t'); layout (b,t',w)
      float s = 0.f;
      const float* ax = &attx_l[bS * T_ + tS];
#pragma unroll
      for (int uc = 0; uc < 16; ++uc) {
        float e = tanh_fast(ax[uc * (GB * T_)] + hU_s[bS][uc]);
        s += e * Vs_l[uc];
      }
      pub_f32(fast, &spg[((size_t)bS * T_ + tS) * WPG + w], s);
    }
    grp_arrive(slots, w, ++epoch);  // B1 arrive

    // ===== B1 shadow: the big h@Rk matvec (independent of sp)
    float4 accR[GB];
#pragma unroll
    for (int b = 0; b < GB; ++b) {
      float4 a = make_float4(0.f, 0.f, 0.f, 0.f);
      const float* hp = &h_s[b][tk * 16];
#pragma unroll
      for (int i = 0; i < 16; ++i) {
        float hv = hp[i];
        a.x += hv * Rw[i].x;
        a.y += hv * Rw[i].y;
        a.z += hv * Rw[i].z;
        a.w += hv * Rw[i].w;
      }
      accR[b] = a;
    }
    grp_wait(fast, slots, epoch, &esc_s);  // B1 wait
    inv_l1(fast);                          // L1 clean before fast gathers

    // ===== P2: wide gather -> softmax (no max pass) -> fold -> LSTM
    {
      const float* spp = spg + ((size_t)bS * T_ + tS) * WPG;
      float4 a0, a1, a2, a3, a4, a5, a6, a7;
      gather32(fast, spp, a0, a1, a2, a3, a4, a5, a6, a7);
      float s = (((a0.x + a0.y) + (a0.z + a0.w)) + ((a1.x + a1.y) + (a1.z + a1.w))) +
                (((a2.x + a2.y) + (a2.z + a2.w)) + ((a3.x + a3.y) + (a3.z + a3.w))) +
                (((a4.x + a4.y) + (a4.z + a4.w)) + ((a5.x + a5.y) + (a5.z + a5.w))) +
                (((a6.x + a6.y) + (a6.z + a6.w)) + ((a7.x + a7.y) + (a7.z + a7.w)));
      float e = __expf(s);  // |s| <= ||V||_1 ~ 20: fp32-safe without shift
      sc_s[bS][tS] = e;
      float ls = e;  // lanes of this wave share bS
      for (int o = 32; o > 0; o >>= 1) ls += __shfl_down(ls, o);
      if (lane == 0) lsum_s[wv] = ls;
    }
    __syncthreads();
#pragma unroll
    for (int b = 0; b < GB; ++b) {
      float4 az = make_float4(0.f, 0.f, 0.f, 0.f);
#pragma unroll
      for (int i = 0; i < 4; ++i) {
        ushort4 xv = xA_l[b][tk * 4 + i][tc];
        float al = sc_s[b][tk * 4 + i];
        az.x += al * bf2f(xv.x);
        az.y += al * bf2f(xv.y);
        az.z += al * bf2f(xv.z);
        az.w += al * bf2f(xv.w);
      }
      float il = 1.f / (lsum_s[2 * b] + lsum_s[2 * b + 1]);
      float4 comb;
      comb.x = accR[b].x + il * az.x;
      comb.y = accR[b].y + il * az.y;
      comb.z = accR[b].z + il * az.z;
      comb.w = accR[b].w + il * az.w;
      comb.x += __shfl_down(comb.x, 32);
      comb.y += __shfl_down(comb.y, 32);
      comb.z += __shfl_down(comb.z, 32);
      comb.w += __shfl_down(comb.w, 32);
      comb.x += __shfl_down(comb.x, 16);
      comb.y += __shfl_down(comb.y, 16);
      comb.z += __shfl_down(comb.z, 16);
      comb.w += __shfl_down(comb.w, 16);
      if (lane < 16) red2[wv][b][lane] = comb;
    }
    __syncthreads();
    if (tid < 256) {
      float gsum = xkv;
      const float* r2 = (const float*)red2;
#pragma unroll
      for (int k = 0; k < 8; ++k)
        gsum += r2[(((size_t)(k * GB + rb) * 17) + rtc) * 4 + rcomp];
      float gv = (rg == 2) ? tanh_fast(gsum)
                           : fminf(fmaxf(0.2f * gsum + 0.5f, 0.f), 1.f);
      act_s[rb][rg * 16 + rui] = gv;
    }
    __syncthreads();
    if (tid < 64) {  // widened LSTM tail: 1 u per lane (R8-verified win)
      int b = tid >> 4, ui = tid & 15;
      float i_ = act_s[b][ui];
      float f_ = act_s[b][16 + ui];
      float g_ = act_s[b][32 + ui];
      float o_ = act_s[b][48 + ui];
      float cn = f_ * c_s[b][ui] + i_ * g_;
      c_s[b][ui] = cn;
      float hv = o_ * tanh_fast(cn);
      int gb = bg * GB + b;
      pub_f32(fast, &hpg[(size_t)b * U_ + u0 + ui], hv);
      out[((size_t)gb * T_ + t) * U_ + u0 + ui] = hv;
    }
    grp_arrive(slots, w, ++epoch);  // B2 arrive

    // ===== B2 shadow: prefetch next step's xk
    int tn = (t + 1 < T_) ? t + 1 : t;
    float xkv_n = 0.f;
    if (tid < 256)
      xkv_n = bf2f(xk[((size_t)(bg * GB + rb) * T_ + tn) * G_ + rcol]);
    grp_wait(fast, slots, epoch, &esc_s);  // B2 wait
    inv_l1(fast);                          // L1 clean before h gather

    {
      float4 hv = load4_coh(fast, hpg + tid * 4);
      *(float4*)&((float*)h_s)[tid * 4] = hv;
    }
    xkv = xkv_n;
    __syncthreads();
  }
}

// ---------------------------------------------------------------------------
extern "C" void kernel_launch(void* const* d_in, const int* in_sizes, int n_in,
                              void* d_out, int out_size, void* d_ws,
                              size_t ws_size, hipStream_t stream) {
  (void)in_sizes;
  (void)n_in;
  (void)out_size;
  (void)ws_size;
  const float* x = (const float*)d_in[0];
  const float* Wk = (const float*)d_in[1];
  const float* Rk = (const float*)d_in[2];
  const float* Ak = (const float*)d_in[3];
  const float* Wa = (const float*)d_in[4];
  const float* Ua = (const float*)d_in[5];
  const float* Va = (const float*)d_in[6];
  const float* bias = (const float*)d_in[7];
  const float* ba = (const float*)d_in[8];
  float* out = (float*)d_out;

  char* ws = (char*)d_ws;
  unsigned short* xk_b = (unsigned short*)(ws);            // 16 MiB
  unsigned short* xA_b = (unsigned short*)(ws + 16777216); // 16 MiB
  float* attxT = (float*)(ws + 33554432);                  // 8 MiB
  float* h_pub = (float*)(ws + 41943040);                  // 64 KiB
  float* sp_g = (float*)(ws + 42008576);                   // 512 KiB
  unsigned* bars = (unsigned*)(ws + 42532864);             // 16 KiB

  gemm_bias_t<1><<<dim3(G_ / 64, (B_ * T_) / 64), 256, 0, stream>>>(
      x, Wk, bias, xk_b, G_);
  gemm_bias_t<1><<<dim3(G_ / 64, (B_ * T_) / 64), 256, 0, stream>>>(
      x, Ak, nullptr, xA_b, G_);
  gemm_bias_t<2><<<dim3(U_ / 64, (B_ * T_) / 64), 256, 0, stream>>>(
      x, Wa, ba, attxT, U_);
  (void)hipMemsetAsync(bars, 0, NGRP * WPG * SLOTSTRIDE * sizeof(unsigned),
                       stream);

  attlstm_rec<<<dim3(NGRP * WPG), dim3(NT), 0, stream>>>(
      xk_b, xA_b, attxT, Rk, Ua, Va, h_pub, sp_g, bars, out);
}